// Round 1
// baseline (304.370 us; speedup 1.0000x reference)
//
#include <hip/hip_runtime.h>
#include <stdint.h>

typedef unsigned short u16;
typedef __bf16 bf16x8 __attribute__((ext_vector_type(8)));
typedef float floatx4 __attribute__((ext_vector_type(4)));
typedef u16 u16x8 __attribute__((ext_vector_type(8)));

__device__ __forceinline__ float bf2f(u16 u) {
    union { unsigned int i; float f; } v; v.i = ((unsigned int)u) << 16; return v.f;
}
__device__ __forceinline__ u16 f2bf(float f) {
    __bf16 h = (__bf16)f;
    return __builtin_bit_cast(u16, h);
}

// ---------------------------------------------------------------------------
// Fused K+V projection GEMM, 128x128 tile, reg-prefetch pipeline. (unchanged)
// C[6144,2048] = concat(kv1,kv2)[6144,1024] @ W[2048,1024]^T + bias.
// cols 0..1023 -> Kout, 1024..2047 -> Vout (Vout = Kout + 6144*1024).
// ---------------------------------------------------------------------------
__global__ __launch_bounds__(256) void gemm_kv(const float* __restrict__ kv1,
                                               const float* __restrict__ kv2,
                                               const float* __restrict__ W,
                                               const float* __restrict__ bias,
                                               u16* __restrict__ Kout) {
    const int K = 1024;
    __shared__ u16 As[128 * 40];
    __shared__ u16 Bs[128 * 40];
    const int tid = threadIdx.x;
    const int wave = tid >> 6, lane = tid & 63;
    const int lane16 = lane & 15, quad = lane >> 4;
    const int rowBase = blockIdx.y * 128;
    const int colBase = blockIdx.x * 128;
    const int wm = (wave >> 1) * 64, wn = (wave & 1) * 64;

    floatx4 acc[4][4];
    #pragma unroll
    for (int am = 0; am < 4; am++)
        #pragma unroll
        for (int bn = 0; bn < 4; bn++) acc[am][bn] = floatx4{0.f, 0.f, 0.f, 0.f};

    const int srow = tid >> 1, shalf = (tid & 1) * 16;
    const int gA = rowBase + srow;
    int bb_ = gA / 3072, r_ = gA - bb_ * 3072;
    const float* aF = (r_ < 1024) ? (kv1 + ((long long)bb_ * 1024 + r_) * K)
                                  : (kv2 + ((long long)bb_ * 2048 + (r_ - 1024)) * K);
    const float* wF = W + (long long)(colBase + srow) * K;

    floatx4 aR[4], bR[4];
    #pragma unroll
    for (int i = 0; i < 4; i++) {
        aR[i] = *(const floatx4*)(aF + shalf + i * 4);
        bR[i] = *(const floatx4*)(wF + shalf + i * 4);
    }

    for (int k0 = 0; k0 < K; k0 += 32) {
        u16x8 av0, av1, bv0, bv1;
        #pragma unroll
        for (int i = 0; i < 4; i++) {
            av0[i] = f2bf(aR[0][i]); av0[4 + i] = f2bf(aR[1][i]);
            av1[i] = f2bf(aR[2][i]); av1[4 + i] = f2bf(aR[3][i]);
            bv0[i] = f2bf(bR[0][i]); bv0[4 + i] = f2bf(bR[1][i]);
            bv1[i] = f2bf(bR[2][i]); bv1[4 + i] = f2bf(bR[3][i]);
        }
        *(u16x8*)&As[srow * 40 + shalf]     = av0;
        *(u16x8*)&As[srow * 40 + shalf + 8] = av1;
        *(u16x8*)&Bs[srow * 40 + shalf]     = bv0;
        *(u16x8*)&Bs[srow * 40 + shalf + 8] = bv1;
        __syncthreads();

        if (k0 + 32 < K) {
            #pragma unroll
            for (int i = 0; i < 4; i++) {
                aR[i] = *(const floatx4*)(aF + k0 + 32 + shalf + i * 4);
                bR[i] = *(const floatx4*)(wF + k0 + 32 + shalf + i * 4);
            }
        }

        u16x8 afr[4], bfr[4];
        #pragma unroll
        for (int am = 0; am < 4; am++)
            afr[am] = *(const u16x8*)&As[(wm + am * 16 + lane16) * 40 + quad * 8];
        #pragma unroll
        for (int bn = 0; bn < 4; bn++)
            bfr[bn] = *(const u16x8*)&Bs[(wn + bn * 16 + lane16) * 40 + quad * 8];
        #pragma unroll
        for (int am = 0; am < 4; am++)
            #pragma unroll
            for (int bn = 0; bn < 4; bn++)
                acc[am][bn] = __builtin_amdgcn_mfma_f32_16x16x32_bf16(
                    __builtin_bit_cast(bf16x8, afr[am]),
                    __builtin_bit_cast(bf16x8, bfr[bn]), acc[am][bn], 0, 0, 0);
        __syncthreads();
    }

    #pragma unroll
    for (int am = 0; am < 4; am++)
        #pragma unroll
        for (int bn = 0; bn < 4; bn++)
            #pragma unroll
            for (int r = 0; r < 4; r++) {
                int row = rowBase + wm + am * 16 + quad * 4 + r;
                int col = colBase + wn + bn * 16 + lane16;
                float v = acc[am][bn][r] + bias[col];
                long long off = (col < 1024)
                    ? ((long long)row * 1024 + col)
                    : ((long long)6144 * 1024 + (long long)row * 1024 + (col - 1024));
                Kout[off] = f2bf(v);
            }
}

// ---------------------------------------------------------------------------
// MFMA GEMM, 128x64 tile, reg-prefetch pipeline. (unchanged)
// ---------------------------------------------------------------------------
template <int ASRC, bool OUT_F32>
__global__ __launch_bounds__(256) void gemm128(const void* __restrict__ A1v,
                                               const float* __restrict__ W,
                                               const float* __restrict__ bias,
                                               void* __restrict__ Cv) {
    const int K = 1024, N = 1024;
    __shared__ u16 As[128 * 40];
    __shared__ u16 Bs[64 * 40];
    const int tid = threadIdx.x;
    const int wave = tid >> 6, lane = tid & 63;
    const int lane16 = lane & 15, quad = lane >> 4;
    const int rowBase = blockIdx.y * 128;
    const int colBase = blockIdx.x * 64;
    const int wm = (wave >> 1) * 64, wn = (wave & 1) * 32;

    floatx4 acc[4][2];
    #pragma unroll
    for (int am = 0; am < 4; am++)
        #pragma unroll
        for (int bn = 0; bn < 2; bn++) acc[am][bn] = floatx4{0.f, 0.f, 0.f, 0.f};

    const int arow = tid >> 1, ahalf = (tid & 1) * 16;
    const float* aF = nullptr; const u16* aH = nullptr;
    if (ASRC == 0) aF = (const float*)A1v + (long long)(rowBase + arow) * K;
    else           aH = (const u16*)A1v + (long long)(rowBase + arow) * K;
    const int brow = tid >> 2, bcol = (tid & 3) * 8;
    const float* wF = W + (long long)(colBase + brow) * K;

    floatx4 aRf[4]; u16x8 aRh[2]; floatx4 bR[2];
    if (ASRC == 0) {
        #pragma unroll
        for (int i = 0; i < 4; i++) aRf[i] = *(const floatx4*)(aF + ahalf + i * 4);
    } else {
        aRh[0] = *(const u16x8*)(aH + ahalf);
        aRh[1] = *(const u16x8*)(aH + ahalf + 8);
    }
    bR[0] = *(const floatx4*)(wF + bcol);
    bR[1] = *(const floatx4*)(wF + bcol + 4);

    for (int k0 = 0; k0 < K; k0 += 32) {
        u16x8 av0, av1, wv;
        if (ASRC == 0) {
            #pragma unroll
            for (int i = 0; i < 4; i++) {
                av0[i] = f2bf(aRf[0][i]); av0[4 + i] = f2bf(aRf[1][i]);
                av1[i] = f2bf(aRf[2][i]); av1[4 + i] = f2bf(aRf[3][i]);
            }
        } else { av0 = aRh[0]; av1 = aRh[1]; }
        #pragma unroll
        for (int i = 0; i < 4; i++) { wv[i] = f2bf(bR[0][i]); wv[4 + i] = f2bf(bR[1][i]); }
        *(u16x8*)&As[arow * 40 + ahalf]     = av0;
        *(u16x8*)&As[arow * 40 + ahalf + 8] = av1;
        *(u16x8*)&Bs[brow * 40 + bcol]      = wv;
        __syncthreads();

        if (k0 + 32 < K) {
            if (ASRC == 0) {
                #pragma unroll
                for (int i = 0; i < 4; i++) aRf[i] = *(const floatx4*)(aF + k0 + 32 + ahalf + i * 4);
            } else {
                aRh[0] = *(const u16x8*)(aH + k0 + 32 + ahalf);
                aRh[1] = *(const u16x8*)(aH + k0 + 32 + ahalf + 8);
            }
            bR[0] = *(const floatx4*)(wF + k0 + 32 + bcol);
            bR[1] = *(const floatx4*)(wF + k0 + 32 + bcol + 4);
        }

        u16x8 afr[4], bfr[2];
        #pragma unroll
        for (int am = 0; am < 4; am++)
            afr[am] = *(const u16x8*)&As[(wm + am * 16 + lane16) * 40 + quad * 8];
        #pragma unroll
        for (int bn = 0; bn < 2; bn++)
            bfr[bn] = *(const u16x8*)&Bs[(wn + bn * 16 + lane16) * 40 + quad * 8];
        #pragma unroll
        for (int am = 0; am < 4; am++)
            #pragma unroll
            for (int bn = 0; bn < 2; bn++)
                acc[am][bn] = __builtin_amdgcn_mfma_f32_16x16x32_bf16(
                    __builtin_bit_cast(bf16x8, afr[am]),
                    __builtin_bit_cast(bf16x8, bfr[bn]), acc[am][bn], 0, 0, 0);
        __syncthreads();
    }

    #pragma unroll
    for (int am = 0; am < 4; am++)
        #pragma unroll
        for (int bn = 0; bn < 2; bn++)
            #pragma unroll
            for (int r = 0; r < 4; r++) {
                int row = rowBase + wm + am * 16 + quad * 4 + r;
                int col = colBase + wn + bn * 16 + lane16;
                float v = acc[am][bn][r] + bias[col];
                if (OUT_F32) ((float*)Cv)[(long long)row * N + col] = v;
                else         ((u16*)Cv)[(long long)row * N + col] = f2bf(v);
            }
}

// ---------------------------------------------------------------------------
// MFMA flash attention, 3-way KEY-SEGMENT SPLIT.
// Old: 512 blocks, 2/CU; the 48-tile block ran ~45 tiles with no co-resident
// partner -> serial chain latency exposed (~4.4k cyc/tile, MfmaUtil 5.8%).
// New: one block per (b,h,qt,seg): 1536 blocks, max chain 16 tiles, 5
// resident blocks/CU. Blocks emit UNNORMALIZED O + (m,l) fp32 partials;
// attn_combine merges the 3 segments. Inner tile code identical to verified.
// ---------------------------------------------------------------------------
__global__ __launch_bounds__(256) void attn_seg(const u16* __restrict__ Q,
                                                const u16* __restrict__ Kb,
                                                const u16* __restrict__ Vb,
                                                float* __restrict__ pO_lo,
                                                float* __restrict__ pO_hi,
                                                float* __restrict__ pml) {
    __shared__ u16 Vt[2][64 * 80];
    __shared__ u16 Ps[4][16 * 80];
    const int tid = threadIdx.x;
    const int wave = tid >> 6, lane = tid & 63;
    const int lane16 = lane & 15, quad = lane >> 4;
    const int idx_ = blockIdx.x;                 // seg*512 + b*256 + h*16 + qhat
    const int qhat = idx_ & 15;
    const int h   = (idx_ >> 4) & 15;
    const int b   = (idx_ >> 8) & 1;
    const int seg = idx_ >> 9;
    const int qt = b ? (15 - qhat) : qhat;       // mixes long/short streams per CU
    const int l0 = qt * 64;
    const int wq = wave * 16;
    const float scale = 0.125f;

    bf16x8 qf[2];
    {
        const u16* qrow = Q + ((long long)(b * 1024 + l0 + wq + lane16)) * 1024 + h * 64;
        qf[0] = __builtin_bit_cast(bf16x8, *(const u16x8*)(qrow + quad * 8));
        qf[1] = __builtin_bit_cast(bf16x8, *(const u16x8*)(qrow + 32 + quad * 8));
    }

    const int skey = tid >> 2, sdb = (tid & 3) * 16;
    const long long bh = ((long long)b * 3072) * 1024 + h * 64;

    u16x8 kr[8], vr0, vr1;
    {
        long long o = bh + ((long long)(seg * 1024)) * 1024;   // tile t=0 of this seg
        vr0 = *(const u16x8*)(Vb + o + (long long)skey * 1024 + sdb);
        vr1 = *(const u16x8*)(Vb + o + (long long)skey * 1024 + sdb + 8);
        #pragma unroll
        for (int c = 0; c < 2; c++)
            #pragma unroll
            for (int mi = 0; mi < 4; mi++)
                kr[c * 4 + mi] = *(const u16x8*)(Kb + o + (long long)(mi * 16 + lane16) * 1024 + c * 32 + quad * 8);
    }
    #pragma unroll
    for (int i = 0; i < 8; i++) {
        Vt[0][(sdb + i) * 80 + skey]     = vr0[i];
        Vt[0][(sdb + 8 + i) * 80 + skey] = vr1[i];
    }
    __syncthreads();

    float m_i = -1e30f, l_i = 0.f;
    floatx4 o_acc[4];
    #pragma unroll
    for (int mi = 0; mi < 4; mi++) o_acc[mi] = floatx4{0.f, 0.f, 0.f, 0.f};

    for (int t = 0; t <= qt; t++) {
        const int cur = t & 1;
        const bool haveNext = t < qt;

        u16x8 nkr[8], nvr0, nvr1;
        if (haveNext) {
            long long o = bh + ((long long)(seg * 1024 + (t + 1) * 64)) * 1024;
            nvr0 = *(const u16x8*)(Vb + o + (long long)skey * 1024 + sdb);
            nvr1 = *(const u16x8*)(Vb + o + (long long)skey * 1024 + sdb + 8);
            #pragma unroll
            for (int c = 0; c < 2; c++)
                #pragma unroll
                for (int mi = 0; mi < 4; mi++)
                    nkr[c * 4 + mi] = *(const u16x8*)(Kb + o + (long long)(mi * 16 + lane16) * 1024 + c * 32 + quad * 8);
        }

        floatx4 sacc[4];
        #pragma unroll
        for (int mi = 0; mi < 4; mi++) sacc[mi] = floatx4{0.f, 0.f, 0.f, 0.f};
        #pragma unroll
        for (int c = 0; c < 2; c++)
            #pragma unroll
            for (int mi = 0; mi < 4; mi++)
                sacc[mi] = __builtin_amdgcn_mfma_f32_16x16x32_bf16(
                    __builtin_bit_cast(bf16x8, kr[c * 4 + mi]), qf[c], sacc[mi], 0, 0, 0);

        const bool diag = (t == qt);             // diag tile repeats in every seg
        const int qloc = wq + lane16;
        float tmax = -1e30f;
        #pragma unroll
        for (int mi = 0; mi < 4; mi++)
            #pragma unroll
            for (int r = 0; r < 4; r++) {
                float s = sacc[mi][r] * scale;
                if (diag && (mi * 16 + quad * 4 + r) > qloc) s = -1e30f;
                sacc[mi][r] = s;
                tmax = fmaxf(tmax, s);
            }
        tmax = fmaxf(tmax, __shfl_xor(tmax, 16));
        tmax = fmaxf(tmax, __shfl_xor(tmax, 32));
        float m_new = fmaxf(m_i, tmax);
        float alpha = __expf(m_i - m_new);
        float psum = 0.f;
        #pragma unroll
        for (int mi = 0; mi < 4; mi++)
            #pragma unroll
            for (int r = 0; r < 4; r++) {
                float p = __expf(sacc[mi][r] - m_new);
                psum += p;
                Ps[wave][lane16 * 80 + mi * 16 + quad * 4 + r] = f2bf(p);
            }
        psum += __shfl_xor(psum, 16);
        psum += __shfl_xor(psum, 32);
        m_i = m_new;
        l_i = l_i * alpha + psum;
        #pragma unroll
        for (int mi = 0; mi < 4; mi++)
            #pragma unroll
            for (int r = 0; r < 4; r++) o_acc[mi][r] *= alpha;

        __builtin_amdgcn_wave_barrier();

        #pragma unroll
        for (int c = 0; c < 2; c++) {
            bf16x8 pf = __builtin_bit_cast(bf16x8,
                *(const u16x8*)&Ps[wave][lane16 * 80 + c * 32 + quad * 8]);
            #pragma unroll
            for (int mi = 0; mi < 4; mi++) {
                bf16x8 vf = __builtin_bit_cast(bf16x8,
                    *(const u16x8*)&Vt[cur][(mi * 16 + lane16) * 80 + c * 32 + quad * 8]);
                o_acc[mi] = __builtin_amdgcn_mfma_f32_16x16x32_bf16(vf, pf, o_acc[mi], 0, 0, 0);
            }
        }

        if (haveNext) {
            #pragma unroll
            for (int i = 0; i < 8; i++) {
                Vt[cur ^ 1][(sdb + i) * 80 + skey]     = nvr0[i];
                Vt[cur ^ 1][(sdb + 8 + i) * 80 + skey] = nvr1[i];
            }
            #pragma unroll
            for (int i = 0; i < 8; i++) kr[i] = nkr[i];
            __syncthreads();
        }
    }

    // ---- emit partials (unnormalized O, running m and l) ----
    const int p = ((b * 16 + h) * 16 + qt) * 3 + seg;     // 0..1535
    float* op = (p < 512) ? (pO_lo + (long long)p * 4096)
                          : (pO_hi + (long long)(p - 512) * 4096);
    if (quad == 0) {     // m_i/l_i uniform across the 4 quads after shfl reduce
        pml[(long long)p * 128 + (wq + lane16) * 2]     = m_i;
        pml[(long long)p * 128 + (wq + lane16) * 2 + 1] = l_i;
    }
    float* orow = op + (long long)(wq + lane16) * 64;     // [query][dim] fp32
    #pragma unroll
    for (int mi = 0; mi < 4; mi++)
        *(floatx4*)(orow + mi * 16 + quad * 4) = o_acc[mi];
}

// ---------------------------------------------------------------------------
// Merge the 3 segment-partials per (b,h,qt): standard flash combine.
// ctx = sum_s exp(m_s - M) O_s / sum_s exp(m_s - M) l_s,  M = max_s m_s.
// ---------------------------------------------------------------------------
__global__ __launch_bounds__(256) void attn_combine(const float* __restrict__ pO_lo,
                                                    const float* __restrict__ pO_hi,
                                                    const float* __restrict__ pml,
                                                    u16* __restrict__ Ctx) {
    const int g = blockIdx.x;            // b*256 + h*16 + qt
    const int qt = g & 15;
    const int h  = (g >> 4) & 15;
    const int b  = g >> 8;
    const int t  = threadIdx.x;
    const int q  = t >> 2;               // 0..63 query within tile
    const int d0 = (t & 3) * 16;         // 16 dims per thread
    const int p0 = g * 3;

    float m[3], l[3];
    #pragma unroll
    for (int s = 0; s < 3; s++) {
        m[s] = pml[(long long)(p0 + s) * 128 + q * 2];
        l[s] = pml[(long long)(p0 + s) * 128 + q * 2 + 1];
    }
    float M = fmaxf(m[0], fmaxf(m[1], m[2]));
    float w[3];
    #pragma unroll
    for (int s = 0; s < 3; s++) w[s] = __expf(m[s] - M);
    float L = w[0] * l[0] + w[1] * l[1] + w[2] * l[2];
    float invL = 1.0f / L;

    const float* O[3];
    #pragma unroll
    for (int s = 0; s < 3; s++) {
        int pp = p0 + s;
        O[s] = ((pp < 512) ? (pO_lo + (long long)pp * 4096)
                           : (pO_hi + (long long)(pp - 512) * 4096))
               + (long long)q * 64 + d0;
    }

    long long crow = ((long long)(b * 1024 + qt * 64 + q)) * 1024 + h * 64 + d0;
    #pragma unroll
    for (int i = 0; i < 16; i += 4) {
        floatx4 a  = *(const floatx4*)(O[0] + i);
        floatx4 bb = *(const floatx4*)(O[1] + i);
        floatx4 cc = *(const floatx4*)(O[2] + i);
        #pragma unroll
        for (int j = 0; j < 4; j++)
            Ctx[crow + i + j] = f2bf((w[0] * a[j] + w[1] * bb[j] + w[2] * cc[j]) * invL);
    }
}

// ---------------------------------------------------------------------------
// residual + LayerNorm + mask. (unchanged)
// ---------------------------------------------------------------------------
__global__ __launch_bounds__(256) void ln_kernel(const float* __restrict__ AO,
                                                 const float* __restrict__ HQ,
                                                 const float* __restrict__ g,
                                                 const float* __restrict__ bb,
                                                 const float* __restrict__ mask,
                                                 float* __restrict__ Out) {
    const int row = blockIdx.x;
    const int t = threadIdx.x;
    const int base = row * 1024 + t * 4;
    floatx4 a  = *(const floatx4*)&AO[base];
    floatx4 hq = *(const floatx4*)&HQ[base];
    float x[4];
    #pragma unroll
    for (int i = 0; i < 4; i++) x[i] = a[i] + hq[i];
    float s = x[0] + x[1] + x[2] + x[3];
    float ss = x[0]*x[0] + x[1]*x[1] + x[2]*x[2] + x[3]*x[3];
    #pragma unroll
    for (int off = 32; off >= 1; off >>= 1) { s += __shfl_xor(s, off); ss += __shfl_xor(ss, off); }
    __shared__ float smem[8];
    int wave = t >> 6, lane = t & 63;
    if (lane == 0) { smem[wave] = s; smem[4 + wave] = ss; }
    __syncthreads();
    s  = smem[0] + smem[1] + smem[2] + smem[3];
    ss = smem[4] + smem[5] + smem[6] + smem[7];
    float mu  = s * (1.f / 1024.f);
    float var = ss * (1.f / 1024.f) - mu * mu;
    float rs  = rsqrtf(var + 1e-5f);
    float mv  = mask[row];
    floatx4 g4 = *(const floatx4*)&g[t * 4];
    floatx4 b4 = *(const floatx4*)&bb[t * 4];
    floatx4 y4;
    #pragma unroll
    for (int i = 0; i < 4; i++) y4[i] = ((x[i] - mu) * rs * g4[i] + b4[i]) * mv;
    *(floatx4*)&Out[base] = y4;
}

// ---------------------------------------------------------------------------
// Workspace map (high-water 44.75 MB):
//   ws+0      q_b (4 MB bf16)  -> ctx (bf16) in-place after combine
//   ws+4 MB   k_b (12 MB bf16) -> ao (fp32 8 MB) after attention
//   ws+16 MB  v_b (12 MB bf16)
//   ws+28 MB  pO_hi (16 MB fp32)  attn partials p=512..1535
//   ws+44 MB  pml   (0.75 MB fp32) attn (m,l) partials
//   d_out (8 MB) doubles as pO_lo (partials p=0..511) until ln overwrites it.
// ---------------------------------------------------------------------------
extern "C" void kernel_launch(void* const* d_in, const int* in_sizes, int n_in,
                              void* d_out, int out_size, void* d_ws, size_t ws_size,
                              hipStream_t stream) {
    (void)in_sizes; (void)n_in; (void)out_size; (void)ws_size;
    const float* h_q   = (const float*)d_in[0];
    const float* h_kv1 = (const float*)d_in[1];
    const float* h_kv2 = (const float*)d_in[2];
    const float* maskp = (const float*)d_in[3];
    const float* win   = (const float*)d_in[4];
    const float* binp  = (const float*)d_in[5];
    const float* wout  = (const float*)d_in[6];
    const float* bout  = (const float*)d_in[7];
    const float* ln_g  = (const float*)d_in[8];
    const float* ln_b  = (const float*)d_in[9];
    float* outp = (float*)d_out;

    char* ws = (char*)d_ws;
    const size_t MB = 1024 * 1024;
    u16*   q_b   = (u16*)(ws);
    u16*   k_b   = (u16*)(ws + 4 * MB);
    u16*   v_b   = (u16*)(ws + 16 * MB);
    u16*   ctx_b = q_b;
    float* ao    = (float*)(ws + 4 * MB);
    float* pO_lo = (float*)d_out;              // scratch until ln writes output
    float* pO_hi = (float*)(ws + 28 * MB);
    float* pml   = (float*)(ws + 44 * MB);

    gemm128<0, false><<<dim3(16, 16), 256, 0, stream>>>(h_q, win, binp, (void*)q_b);
    gemm_kv<<<dim3(16, 48), 256, 0, stream>>>(h_kv1, h_kv2, win + 1024 * 1024, binp + 1024, k_b);
    attn_seg<<<1536, 256, 0, stream>>>(q_b, k_b, v_b, pO_lo, pO_hi, pml);
    attn_combine<<<512, 256, 0, stream>>>(pO_lo, pO_hi, pml, ctx_b);
    gemm128<2, true><<<dim3(16, 16), 256, 0, stream>>>(ctx_b, wout, bout, (void*)ao);
    ln_kernel<<<2048, 256, 0, stream>>>(ao, h_q, ln_g, ln_b, maskp, outp);
}

// Round 2
// 278.443 us; speedup vs baseline: 1.0931x; 1.0931x over previous
//
#include <hip/hip_runtime.h>
#include <stdint.h>

typedef unsigned short u16;
typedef unsigned int u32;
typedef __bf16 bf16x8 __attribute__((ext_vector_type(8)));
typedef float floatx4 __attribute__((ext_vector_type(4)));
typedef u16 u16x8 __attribute__((ext_vector_type(8)));

__device__ __forceinline__ u16 f2bf(float f) {
    __bf16 h = (__bf16)f;
    return __builtin_bit_cast(u16, h);
}

// async global->LDS, 16B per lane. LDS dest = wave-uniform base + lane*16.
__device__ __forceinline__ void gll16(const u16* g, u16* l) {
    typedef __attribute__((address_space(1))) u32 gu32;
    typedef __attribute__((address_space(3))) u32 lu32;
    __builtin_amdgcn_global_load_lds((gu32*)g, (lu32*)l, 16, 0, 0);
}

// ---------------------------------------------------------------------------
// fp32 -> bf16 elementwise convert (8 elems/thread/iter, grid-stride).
// ---------------------------------------------------------------------------
__global__ __launch_bounds__(256) void cvt_bf16(const float* __restrict__ in,
                                                u16* __restrict__ out, int n8) {
    int i = blockIdx.x * 256 + threadIdx.x;
    const int stride = gridDim.x * 256;
    for (; i < n8; i += stride) {
        floatx4 a = *(const floatx4*)(in + (long long)i * 8);
        floatx4 b = *(const floatx4*)(in + (long long)i * 8 + 4);
        u16x8 o;
        #pragma unroll
        for (int j = 0; j < 4; j++) { o[j] = f2bf(a[j]); o[4 + j] = f2bf(b[j]); }
        *(u16x8*)(out + (long long)i * 8) = o;
    }
}

// ---------------------------------------------------------------------------
// Fused Q+K+V projection. 896 blocks (128 q-blocks + 768 kv-blocks), 128x128
// tile, BK=32. A (fp32 h_q / h_kv) reg-prefetched + cvt'd (prefetch now LIVES
// across the raw ending barrier -> HBM latency hidden over a full iter).
// B (pre-converted bf16 W) staged via global_load_lds (no VALU, L2-resident).
// ---------------------------------------------------------------------------
__global__ __launch_bounds__(256) void gemm_proj(const float* __restrict__ hq,
                                                 const float* __restrict__ kv1,
                                                 const float* __restrict__ kv2,
                                                 const u16* __restrict__ wb,
                                                 const float* __restrict__ bias,
                                                 u16* __restrict__ Qo,
                                                 u16* __restrict__ Ko,
                                                 u16* __restrict__ Vo) {
    const int K = 1024;
    __shared__ u16 As[128 * 40];      // padded (ds_write path, pad OK)
    __shared__ u16 Bs[128 * 32];      // linear (global_load_lds: no pad allowed)
    const int tid = threadIdx.x;
    const int wave = tid >> 6, lane = tid & 63;
    const int lane16 = lane & 15, quad = lane >> 4;

    // XCD swizzle: 896 % 8 == 0 -> 112 contiguous blocks per XCD
    const int bid = blockIdx.x;
    const int g = (bid & 7) * 112 + (bid >> 3);
    const bool qblk = g < 128;
    int my, nx;
    if (qblk) { my = g >> 3; nx = g & 7; }            // 16 x 8
    else { int gg = g - 128; my = gg >> 4; nx = gg & 15; }  // 48 x 16
    const int rowBase = my * 128;
    const int colBase = nx * 128;
    const int wrow = (qblk ? 0 : 1024) + colBase;     // W row = output col
    const int wm = (wave >> 1) * 64, wn = (wave & 1) * 64;

    floatx4 acc[4][4];
    #pragma unroll
    for (int am = 0; am < 4; am++)
        #pragma unroll
        for (int bn = 0; bn < 4; bn++) acc[am][bn] = floatx4{0.f, 0.f, 0.f, 0.f};

    // A staging: row = tid>>1 (0..127), 16 fp32 at (tid&1)*16
    const int srow = tid >> 1, shalf = (tid & 1) * 16;
    const float* aF;
    if (qblk) {
        aF = hq + (long long)(rowBase + srow) * K;
    } else {
        int gA = rowBase + srow;
        int bb_ = gA / 3072, r_ = gA - bb_ * 3072;    // tiles never straddle
        aF = (r_ < 1024) ? (kv1 + ((long long)bb_ * 1024 + r_) * K)
                         : (kv2 + ((long long)bb_ * 2048 + (r_ - 1024)) * K);
    }
    // B gll sources: thread covers row wrow + r*64 + tid/4, col (tid&3)*8
    const u16* wS0 = wb + (long long)(wrow + (tid >> 2)) * K + (tid & 3) * 8;
    const u16* wS1 = wS0 + (long long)64 * K;
    u16* ldsB0 = &Bs[wave * 512];          // bytes: wave*1024 (+lane*16 by HW)
    u16* ldsB1 = &Bs[2048 + wave * 512];

    floatx4 aR[4];
    #pragma unroll
    for (int i = 0; i < 4; i++) aR[i] = *(const floatx4*)(aF + shalf + i * 4);

    for (int k0 = 0; k0 < K; k0 += 32) {
        gll16(wS0 + k0, ldsB0);            // B: async, drained at syncthreads
        gll16(wS1 + k0, ldsB1);
        u16x8 av0, av1;
        #pragma unroll
        for (int i = 0; i < 4; i++) {
            av0[i] = f2bf(aR[0][i]); av0[4 + i] = f2bf(aR[1][i]);
            av1[i] = f2bf(aR[2][i]); av1[4 + i] = f2bf(aR[3][i]);
        }
        *(u16x8*)&As[srow * 40 + shalf]     = av0;
        *(u16x8*)&As[srow * 40 + shalf + 8] = av1;
        __syncthreads();                   // drains B-gll (vm) + A-writes (lgkm)

        if (k0 + 32 < K) {                 // A prefetch: stays in flight across
            #pragma unroll                 // the raw ending barrier below
            for (int i = 0; i < 4; i++)
                aR[i] = *(const floatx4*)(aF + k0 + 32 + shalf + i * 4);
        }

        u16x8 afr[4], bfr[4];
        #pragma unroll
        for (int am = 0; am < 4; am++)
            afr[am] = *(const u16x8*)&As[(wm + am * 16 + lane16) * 40 + quad * 8];
        #pragma unroll
        for (int bn = 0; bn < 4; bn++)
            bfr[bn] = *(const u16x8*)&Bs[(wn + bn * 16 + lane16) * 32 + quad * 8];
        #pragma unroll
        for (int am = 0; am < 4; am++)
            #pragma unroll
            for (int bn = 0; bn < 4; bn++)
                acc[am][bn] = __builtin_amdgcn_mfma_f32_16x16x32_bf16(
                    __builtin_bit_cast(bf16x8, afr[am]),
                    __builtin_bit_cast(bf16x8, bfr[bn]), acc[am][bn], 0, 0, 0);

        // ending barrier WITHOUT vmcnt drain: LDS reads done, waves sync,
        // A-prefetch (vm) survives. sched_barrier pins next iter's ops after.
        asm volatile("s_waitcnt lgkmcnt(0)" ::: "memory");
        __builtin_amdgcn_s_barrier();
        __builtin_amdgcn_sched_barrier(0);
    }

    const float* bcol = bias + (qblk ? 0 : 1024) + colBase;
    u16* Cb; int colLoc;
    if (qblk)       { Cb = Qo; colLoc = colBase; }
    else if (nx < 8){ Cb = Ko; colLoc = colBase; }
    else            { Cb = Vo; colLoc = colBase - 1024; }
    #pragma unroll
    for (int am = 0; am < 4; am++)
        #pragma unroll
        for (int bn = 0; bn < 4; bn++)
            #pragma unroll
            for (int r = 0; r < 4; r++) {
                int row = rowBase + wm + am * 16 + quad * 4 + r;
                int col = wn + bn * 16 + lane16;
                float v = acc[am][bn][r] + bcol[col];
                Cb[(long long)row * 1024 + colLoc + col] = f2bf(v);
            }
}

// ---------------------------------------------------------------------------
// Out-projection, all-global_load_lds (A=ctx bf16, B=wob bf16), split-K=2.
// 256 blocks (16 my x 8 nx x 2 kh), fp32 partials; ln sums them.
// ---------------------------------------------------------------------------
__global__ __launch_bounds__(256) void gemm_out(const u16* __restrict__ ctx,
                                                const u16* __restrict__ wob,
                                                const float* __restrict__ bias,
                                                float* __restrict__ ao0,
                                                float* __restrict__ ao1) {
    const int K = 1024;
    __shared__ u16 As[128 * 32];
    __shared__ u16 Bs[128 * 32];
    const int tid = threadIdx.x;
    const int wave = tid >> 6, lane = tid & 63;
    const int lane16 = lane & 15, quad = lane >> 4;
    const int bid = blockIdx.x;
    const int g = (bid & 7) * 32 + (bid >> 3);        // 256 % 8 == 0
    const int my = g >> 4;
    const int nx = (g & 15) >> 1;
    const int kh = g & 1;
    const int rowBase = my * 128, colBase = nx * 128, kbase = kh * 512;
    const int wm = (wave >> 1) * 64, wn = (wave & 1) * 64;

    floatx4 acc[4][4];
    #pragma unroll
    for (int am = 0; am < 4; am++)
        #pragma unroll
        for (int bn = 0; bn < 4; bn++) acc[am][bn] = floatx4{0.f, 0.f, 0.f, 0.f};

    const u16* aS0 = ctx + (long long)(rowBase + (tid >> 2)) * K + kbase + (tid & 3) * 8;
    const u16* aS1 = aS0 + (long long)64 * K;
    const u16* wS0 = wob + (long long)(colBase + (tid >> 2)) * K + kbase + (tid & 3) * 8;
    const u16* wS1 = wS0 + (long long)64 * K;
    u16* ldsA0 = &As[wave * 512];
    u16* ldsA1 = &As[2048 + wave * 512];
    u16* ldsB0 = &Bs[wave * 512];
    u16* ldsB1 = &Bs[2048 + wave * 512];

    for (int k0 = 0; k0 < 512; k0 += 32) {
        gll16(aS0 + k0, ldsA0);
        gll16(aS1 + k0, ldsA1);
        gll16(wS0 + k0, ldsB0);
        gll16(wS1 + k0, ldsB1);
        __syncthreads();

        u16x8 afr[4], bfr[4];
        #pragma unroll
        for (int am = 0; am < 4; am++)
            afr[am] = *(const u16x8*)&As[(wm + am * 16 + lane16) * 32 + quad * 8];
        #pragma unroll
        for (int bn = 0; bn < 4; bn++)
            bfr[bn] = *(const u16x8*)&Bs[(wn + bn * 16 + lane16) * 32 + quad * 8];
        #pragma unroll
        for (int am = 0; am < 4; am++)
            #pragma unroll
            for (int bn = 0; bn < 4; bn++)
                acc[am][bn] = __builtin_amdgcn_mfma_f32_16x16x32_bf16(
                    __builtin_bit_cast(bf16x8, afr[am]),
                    __builtin_bit_cast(bf16x8, bfr[bn]), acc[am][bn], 0, 0, 0);
        __syncthreads();
    }

    float* Co = kh ? ao1 : ao0;
    #pragma unroll
    for (int am = 0; am < 4; am++)
        #pragma unroll
        for (int bn = 0; bn < 4; bn++)
            #pragma unroll
            for (int r = 0; r < 4; r++) {
                int row = rowBase + wm + am * 16 + quad * 4 + r;
                int col = colBase + wn + bn * 16 + lane16;
                float v = acc[am][bn][r] + (kh == 0 ? bias[col] : 0.f);
                Co[(long long)row * 1024 + col] = v;
            }
}

// ---------------------------------------------------------------------------
// MFMA flash attention, 3-way key-segment split. (verbatim from passing R1)
// ---------------------------------------------------------------------------
__global__ __launch_bounds__(256) void attn_seg(const u16* __restrict__ Q,
                                                const u16* __restrict__ Kb,
                                                const u16* __restrict__ Vb,
                                                float* __restrict__ pO_lo,
                                                float* __restrict__ pO_hi,
                                                float* __restrict__ pml) {
    __shared__ u16 Vt[2][64 * 80];
    __shared__ u16 Ps[4][16 * 80];
    const int tid = threadIdx.x;
    const int wave = tid >> 6, lane = tid & 63;
    const int lane16 = lane & 15, quad = lane >> 4;
    const int idx_ = blockIdx.x;                 // seg*512 + b*256 + h*16 + qhat
    const int qhat = idx_ & 15;
    const int h   = (idx_ >> 4) & 15;
    const int b   = (idx_ >> 8) & 1;
    const int seg = idx_ >> 9;
    const int qt = b ? (15 - qhat) : qhat;
    const int l0 = qt * 64;
    const int wq = wave * 16;
    const float scale = 0.125f;

    bf16x8 qf[2];
    {
        const u16* qrow = Q + ((long long)(b * 1024 + l0 + wq + lane16)) * 1024 + h * 64;
        qf[0] = __builtin_bit_cast(bf16x8, *(const u16x8*)(qrow + quad * 8));
        qf[1] = __builtin_bit_cast(bf16x8, *(const u16x8*)(qrow + 32 + quad * 8));
    }

    const int skey = tid >> 2, sdb = (tid & 3) * 16;
    const long long bh = ((long long)b * 3072) * 1024 + h * 64;

    u16x8 kr[8], vr0, vr1;
    {
        long long o = bh + ((long long)(seg * 1024)) * 1024;
        vr0 = *(const u16x8*)(Vb + o + (long long)skey * 1024 + sdb);
        vr1 = *(const u16x8*)(Vb + o + (long long)skey * 1024 + sdb + 8);
        #pragma unroll
        for (int c = 0; c < 2; c++)
            #pragma unroll
            for (int mi = 0; mi < 4; mi++)
                kr[c * 4 + mi] = *(const u16x8*)(Kb + o + (long long)(mi * 16 + lane16) * 1024 + c * 32 + quad * 8);
    }
    #pragma unroll
    for (int i = 0; i < 8; i++) {
        Vt[0][(sdb + i) * 80 + skey]     = vr0[i];
        Vt[0][(sdb + 8 + i) * 80 + skey] = vr1[i];
    }
    __syncthreads();

    float m_i = -1e30f, l_i = 0.f;
    floatx4 o_acc[4];
    #pragma unroll
    for (int mi = 0; mi < 4; mi++) o_acc[mi] = floatx4{0.f, 0.f, 0.f, 0.f};

    for (int t = 0; t <= qt; t++) {
        const int cur = t & 1;
        const bool haveNext = t < qt;

        u16x8 nkr[8], nvr0, nvr1;
        if (haveNext) {
            long long o = bh + ((long long)(seg * 1024 + (t + 1) * 64)) * 1024;
            nvr0 = *(const u16x8*)(Vb + o + (long long)skey * 1024 + sdb);
            nvr1 = *(const u16x8*)(Vb + o + (long long)skey * 1024 + sdb + 8);
            #pragma unroll
            for (int c = 0; c < 2; c++)
                #pragma unroll
                for (int mi = 0; mi < 4; mi++)
                    nkr[c * 4 + mi] = *(const u16x8*)(Kb + o + (long long)(mi * 16 + lane16) * 1024 + c * 32 + quad * 8);
        }

        floatx4 sacc[4];
        #pragma unroll
        for (int mi = 0; mi < 4; mi++) sacc[mi] = floatx4{0.f, 0.f, 0.f, 0.f};
        #pragma unroll
        for (int c = 0; c < 2; c++)
            #pragma unroll
            for (int mi = 0; mi < 4; mi++)
                sacc[mi] = __builtin_amdgcn_mfma_f32_16x16x32_bf16(
                    __builtin_bit_cast(bf16x8, kr[c * 4 + mi]), qf[c], sacc[mi], 0, 0, 0);

        const bool diag = (t == qt);
        const int qloc = wq + lane16;
        float tmax = -1e30f;
        #pragma unroll
        for (int mi = 0; mi < 4; mi++)
            #pragma unroll
            for (int r = 0; r < 4; r++) {
                float s = sacc[mi][r] * scale;
                if (diag && (mi * 16 + quad * 4 + r) > qloc) s = -1e30f;
                sacc[mi][r] = s;
                tmax = fmaxf(tmax, s);
            }
        tmax = fmaxf(tmax, __shfl_xor(tmax, 16));
        tmax = fmaxf(tmax, __shfl_xor(tmax, 32));
        float m_new = fmaxf(m_i, tmax);
        float alpha = __expf(m_i - m_new);
        float psum = 0.f;
        #pragma unroll
        for (int mi = 0; mi < 4; mi++)
            #pragma unroll
            for (int r = 0; r < 4; r++) {
                float p = __expf(sacc[mi][r] - m_new);
                psum += p;
                Ps[wave][lane16 * 80 + mi * 16 + quad * 4 + r] = f2bf(p);
            }
        psum += __shfl_xor(psum, 16);
        psum += __shfl_xor(psum, 32);
        m_i = m_new;
        l_i = l_i * alpha + psum;
        #pragma unroll
        for (int mi = 0; mi < 4; mi++)
            #pragma unroll
            for (int r = 0; r < 4; r++) o_acc[mi][r] *= alpha;

        __builtin_amdgcn_wave_barrier();

        #pragma unroll
        for (int c = 0; c < 2; c++) {
            bf16x8 pf = __builtin_bit_cast(bf16x8,
                *(const u16x8*)&Ps[wave][lane16 * 80 + c * 32 + quad * 8]);
            #pragma unroll
            for (int mi = 0; mi < 4; mi++) {
                bf16x8 vf = __builtin_bit_cast(bf16x8,
                    *(const u16x8*)&Vt[cur][(mi * 16 + lane16) * 80 + c * 32 + quad * 8]);
                o_acc[mi] = __builtin_amdgcn_mfma_f32_16x16x32_bf16(vf, pf, o_acc[mi], 0, 0, 0);
            }
        }

        if (haveNext) {
            #pragma unroll
            for (int i = 0; i < 8; i++) {
                Vt[cur ^ 1][(sdb + i) * 80 + skey]     = nvr0[i];
                Vt[cur ^ 1][(sdb + 8 + i) * 80 + skey] = nvr1[i];
            }
            #pragma unroll
            for (int i = 0; i < 8; i++) kr[i] = nkr[i];
            __syncthreads();
        }
    }

    const int p = ((b * 16 + h) * 16 + qt) * 3 + seg;     // 0..1535
    float* op = (p < 512) ? (pO_lo + (long long)p * 4096)
                          : (pO_hi + (long long)(p - 512) * 4096);
    if (quad == 0) {
        pml[(long long)p * 128 + (wq + lane16) * 2]     = m_i;
        pml[(long long)p * 128 + (wq + lane16) * 2 + 1] = l_i;
    }
    float* orow = op + (long long)(wq + lane16) * 64;
    #pragma unroll
    for (int mi = 0; mi < 4; mi++)
        *(floatx4*)(orow + mi * 16 + quad * 4) = o_acc[mi];
}

// ---------------------------------------------------------------------------
// Merge the 3 segment-partials per (b,h,qt). (verbatim from passing R1)
// ---------------------------------------------------------------------------
__global__ __launch_bounds__(256) void attn_combine(const float* __restrict__ pO_lo,
                                                    const float* __restrict__ pO_hi,
                                                    const float* __restrict__ pml,
                                                    u16* __restrict__ Ctx) {
    const int g = blockIdx.x;            // b*256 + h*16 + qt
    const int qt = g & 15;
    const int h  = (g >> 4) & 15;
    const int b  = g >> 8;
    const int t  = threadIdx.x;
    const int q  = t >> 2;
    const int d0 = (t & 3) * 16;
    const int p0 = g * 3;

    float m[3], l[3];
    #pragma unroll
    for (int s = 0; s < 3; s++) {
        m[s] = pml[(long long)(p0 + s) * 128 + q * 2];
        l[s] = pml[(long long)(p0 + s) * 128 + q * 2 + 1];
    }
    float M = fmaxf(m[0], fmaxf(m[1], m[2]));
    float w[3];
    #pragma unroll
    for (int s = 0; s < 3; s++) w[s] = __expf(m[s] - M);
    float L = w[0] * l[0] + w[1] * l[1] + w[2] * l[2];
    float invL = 1.0f / L;

    const float* O[3];
    #pragma unroll
    for (int s = 0; s < 3; s++) {
        int pp = p0 + s;
        O[s] = ((pp < 512) ? (pO_lo + (long long)pp * 4096)
                           : (pO_hi + (long long)(pp - 512) * 4096))
               + (long long)q * 64 + d0;
    }

    long long crow = ((long long)(b * 1024 + qt * 64 + q)) * 1024 + h * 64 + d0;
    #pragma unroll
    for (int i = 0; i < 16; i += 4) {
        floatx4 a  = *(const floatx4*)(O[0] + i);
        floatx4 bb = *(const floatx4*)(O[1] + i);
        floatx4 cc = *(const floatx4*)(O[2] + i);
        #pragma unroll
        for (int j = 0; j < 4; j++)
            Ctx[crow + i + j] = f2bf((w[0] * a[j] + w[1] * bb[j] + w[2] * cc[j]) * invL);
    }
}

// ---------------------------------------------------------------------------
// residual + LayerNorm + mask; sums the two split-K out-proj partials.
// ---------------------------------------------------------------------------
__global__ __launch_bounds__(256) void ln_kernel(const float* __restrict__ AO0,
                                                 const float* __restrict__ AO1,
                                                 const float* __restrict__ HQ,
                                                 const float* __restrict__ g,
                                                 const float* __restrict__ bb,
                                                 const float* __restrict__ mask,
                                                 float* __restrict__ Out) {
    const int row = blockIdx.x;
    const int t = threadIdx.x;
    const int base = row * 1024 + t * 4;
    floatx4 a0 = *(const floatx4*)&AO0[base];
    floatx4 a1 = *(const floatx4*)&AO1[base];
    floatx4 hq = *(const floatx4*)&HQ[base];
    float x[4];
    #pragma unroll
    for (int i = 0; i < 4; i++) x[i] = a0[i] + a1[i] + hq[i];
    float s = x[0] + x[1] + x[2] + x[3];
    float ss = x[0]*x[0] + x[1]*x[1] + x[2]*x[2] + x[3]*x[3];
    #pragma unroll
    for (int off = 32; off >= 1; off >>= 1) { s += __shfl_xor(s, off); ss += __shfl_xor(ss, off); }
    __shared__ float smem[8];
    int wave = t >> 6, lane = t & 63;
    if (lane == 0) { smem[wave] = s; smem[4 + wave] = ss; }
    __syncthreads();
    s  = smem[0] + smem[1] + smem[2] + smem[3];
    ss = smem[4] + smem[5] + smem[6] + smem[7];
    float mu  = s * (1.f / 1024.f);
    float var = ss * (1.f / 1024.f) - mu * mu;
    float rs  = rsqrtf(var + 1e-5f);
    float mv  = mask[row];
    floatx4 g4 = *(const floatx4*)&g[t * 4];
    floatx4 b4 = *(const floatx4*)&bb[t * 4];
    floatx4 y4;
    #pragma unroll
    for (int i = 0; i < 4; i++) y4[i] = ((x[i] - mu) * rs * g4[i] + b4[i]) * mv;
    *(floatx4*)&Out[base] = y4;
}

// ---------------------------------------------------------------------------
// Workspace map (high-water 44.75 MB, proven safe in R1):
//   ws+0      q_b  4 MB  (proj out; ctx bf16 in-place after combine)
//   ws+4 MB   k_b 12 MB  (dead after attn -> ao0 fp32 8 MB at ws+4)
//   ws+16 MB  v_b 12 MB  (dead after attn -> ao1 fp32 8 MB at ws+12)
//   ws+28 MB  wb   6 MB (convert->proj) -> pO_hi 16 MB (attn->combine)
//             -> wob 2 MB (cvt after combine -> gemm_out)
//   ws+44 MB  pml 0.75 MB
//   d_out (8 MB) = pO_lo scratch until ln writes the real output.
// ---------------------------------------------------------------------------
extern "C" void kernel_launch(void* const* d_in, const int* in_sizes, int n_in,
                              void* d_out, int out_size, void* d_ws, size_t ws_size,
                              hipStream_t stream) {
    (void)in_sizes; (void)n_in; (void)out_size; (void)ws_size;
    const float* h_q   = (const float*)d_in[0];
    const float* h_kv1 = (const float*)d_in[1];
    const float* h_kv2 = (const float*)d_in[2];
    const float* maskp = (const float*)d_in[3];
    const float* win   = (const float*)d_in[4];
    const float* binp  = (const float*)d_in[5];
    const float* wout  = (const float*)d_in[6];
    const float* bout  = (const float*)d_in[7];
    const float* ln_g  = (const float*)d_in[8];
    const float* ln_b  = (const float*)d_in[9];
    float* outp = (float*)d_out;

    char* ws = (char*)d_ws;
    const size_t MB = 1024 * 1024;
    u16*   q_b   = (u16*)(ws);
    u16*   k_b   = (u16*)(ws + 4 * MB);
    u16*   v_b   = (u16*)(ws + 16 * MB);
    u16*   ctx_b = q_b;
    u16*   wb    = (u16*)(ws + 28 * MB);
    u16*   wob   = (u16*)(ws + 28 * MB);
    float* pO_lo = (float*)d_out;
    float* pO_hi = (float*)(ws + 28 * MB);
    float* pml   = (float*)(ws + 44 * MB);
    float* ao0   = (float*)(ws + 4 * MB);
    float* ao1   = (float*)(ws + 12 * MB);

    cvt_bf16<<<768, 256, 0, stream>>>(win, wb, 3 * 1024 * 1024 / 8);
    gemm_proj<<<896, 256, 0, stream>>>(h_q, h_kv1, h_kv2, wb, binp, q_b, k_b, v_b);
    attn_seg<<<1536, 256, 0, stream>>>(q_b, k_b, v_b, pO_lo, pO_hi, pml);
    attn_combine<<<512, 256, 0, stream>>>(pO_lo, pO_hi, pml, ctx_b);
    cvt_bf16<<<512, 256, 0, stream>>>(wout, wob, 1024 * 1024 / 8);
    gemm_out<<<256, 256, 0, stream>>>(ctx_b, wob, bout, ao0, ao1);
    ln_kernel<<<2048, 256, 0, stream>>>(ao0, ao1, h_q, ln_g, ln_b, maskp, outp);
}

// Round 4
// 241.644 us; speedup vs baseline: 1.2596x; 1.1523x over previous
//
#include <hip/hip_runtime.h>
#include <stdint.h>

typedef unsigned short u16;
typedef unsigned int u32;
typedef __bf16 bf16x8 __attribute__((ext_vector_type(8)));
typedef float floatx4 __attribute__((ext_vector_type(4)));
typedef u16 u16x8 __attribute__((ext_vector_type(8)));

__device__ __forceinline__ u16 f2bf(float f) {
    __bf16 h = (__bf16)f;
    return __builtin_bit_cast(u16, h);
}

// async global->LDS, 16B per lane. LDS dest = wave-uniform base + lane*16.
__device__ __forceinline__ void gll16(const u16* g, u16* l) {
    typedef __attribute__((address_space(1))) u32 gu32;
    typedef __attribute__((address_space(3))) u32 lu32;
    __builtin_amdgcn_global_load_lds((gu32*)g, (lu32*)l, 16, 0, 0);
}

// ---------------------------------------------------------------------------
// One-shot fp32->bf16 convert of h_q, concat(kv1,kv2), and W_in.
// a_q [2048][1024], a_kv [6144][1024] (concat layout), wb [3072][1024].
// ---------------------------------------------------------------------------
__global__ __launch_bounds__(256) void cvt_all(const float* __restrict__ hq,
                                               const float* __restrict__ kv1,
                                               const float* __restrict__ kv2,
                                               const float* __restrict__ win,
                                               u16* __restrict__ a_q,
                                               u16* __restrict__ a_kv,
                                               u16* __restrict__ wb) {
    const int NQ = 262144, NKV = 786432, NW = 393216;   // 8-elem chunks
    int i = blockIdx.x * 256 + threadIdx.x;
    const int stride = gridDim.x * 256;
    for (; i < NQ + NKV + NW; i += stride) {
        const float* src; u16* dst;
        if (i < NQ) {
            src = hq + (long long)i * 8; dst = a_q + (long long)i * 8;
        } else if (i < NQ + NKV) {
            int c = i - NQ;
            int row = c >> 7;                 // 128 chunks per 1024-elem row
            int col = (c & 127) * 8;
            int b = row >= 3072, r = row - b * 3072;
            src = (r < 1024) ? kv1 + ((long long)(b * 1024 + r)) * 1024 + col
                             : kv2 + ((long long)(b * 2048 + (r - 1024))) * 1024 + col;
            dst = a_kv + (long long)row * 1024 + col;
        } else {
            int c = i - (NQ + NKV);
            src = win + (long long)c * 8; dst = wb + (long long)c * 8;
        }
        floatx4 x = *(const floatx4*)src;
        floatx4 y = *(const floatx4*)(src + 4);
        u16x8 o;
        #pragma unroll
        for (int j = 0; j < 4; j++) { o[j] = f2bf(x[j]); o[4 + j] = f2bf(y[j]); }
        *(u16x8*)dst = o;
    }
}

// plain fp32->bf16 flat convert (for W_out, launched after combine)
__global__ __launch_bounds__(256) void cvt_bf16(const float* __restrict__ in,
                                                u16* __restrict__ out, int n8) {
    int i = blockIdx.x * 256 + threadIdx.x;
    const int stride = gridDim.x * 256;
    for (; i < n8; i += stride) {
        floatx4 a = *(const floatx4*)(in + (long long)i * 8);
        floatx4 b = *(const floatx4*)(in + (long long)i * 8 + 4);
        u16x8 o;
        #pragma unroll
        for (int j = 0; j < 4; j++) { o[j] = f2bf(a[j]); o[4 + j] = f2bf(b[j]); }
        *(u16x8*)(out + (long long)i * 8) = o;
    }
}

// ---------------------------------------------------------------------------
// Fused Q+K+V projection. All-bf16, all-global_load_lds, BK=64, double-
// buffered LDS (2 x 32 KB), ONE barrier per K-step: issue next-tile glls,
// then ds_read + 32 MFMA of current tile (~350cyc cover), then syncthreads
// (vmcnt(0) drain lands next tile). Bank-conflict-free via rule-#21:
// linear LDS dest + inverse-XOR global source + XOR'd ds_read slot.
// ---------------------------------------------------------------------------
__global__ __launch_bounds__(256) void gemm_proj(const u16* __restrict__ aq,
                                                 const u16* __restrict__ akv,
                                                 const u16* __restrict__ wb,
                                                 const float* __restrict__ bias,
                                                 u16* __restrict__ Qo,
                                                 u16* __restrict__ Ko,
                                                 u16* __restrict__ Vo) {
    __shared__ u16 lds[2][2][8192];            // [buf][A|B][128 rows x 64 cols]
    const int tid = threadIdx.x;
    const int wave = tid >> 6, lane = tid & 63;
    const int lane16 = lane & 15, quad = lane >> 4;
    const int bid = blockIdx.x;
    const int g = (bid & 7) * 112 + (bid >> 3);   // XCD swizzle, 896%8==0
    const bool qblk = g < 128;
    int my, nx;
    if (qblk) { my = g >> 3; nx = g & 7; }            // 16 x 8
    else { int gg = g - 128; my = gg >> 4; nx = gg & 15; }  // 48 x 16
    const int rowBase = my * 128;
    const int colBase = nx * 128;
    const int wrow = (qblk ? 0 : 1024) + colBase;
    const int wm = (wave >> 1) * 64, wn = (wave & 1) * 64;

    floatx4 acc[4][4];
    #pragma unroll
    for (int am = 0; am < 4; am++)
        #pragma unroll
        for (int bn = 0; bn < 4; bn++) acc[am][bn] = floatx4{0.f, 0.f, 0.f, 0.f};

    // staging: call j covers rows j*32 + tid>>3; source col pre-swizzled so
    // LDS(row, slot) holds global (row, slot ^ (row&7)); rows land linear.
    const int srow8 = tid >> 3;
    const int scol = ((tid & 7) ^ (srow8 & 7)) * 8;
    const u16* aS = (qblk ? aq : akv) + (long long)(rowBase + srow8) * 1024 + scol;
    const u16* bS = wb + (long long)(wrow + srow8) * 1024 + scol;
    u16* lbase = &lds[0][0][0];
    const int ldst = wave * 512;               // u16; HW adds lane*16 B

    // read slot XOR: row&7 == lane16&7 (wm/wn/i*16 are multiples of 8)
    const int cko0 = ((quad ^ (lane16 & 7)) * 8);        // k-half 0
    const int cko1 = (((4 + quad) ^ (lane16 & 7)) * 8);  // k-half 1

    {   // prologue: stage tile 0 into buf 0
        u16* dA = lbase; u16* dB = lbase + 8192;
        #pragma unroll
        for (int j = 0; j < 4; j++) {
            gll16(aS + j * 32768, dA + j * 2048 + ldst);
            gll16(bS + j * 32768, dB + j * 2048 + ldst);
        }
    }
    __syncthreads();

    int buf = 0;
    for (int t = 0; t < 16; t++) {
        if (t < 15) {                          // issue next tile FIRST
            const int k0 = (t + 1) * 64;
            u16* dA = lbase + (buf ^ 1) * 16384;
            u16* dB = dA + 8192;
            #pragma unroll
            for (int j = 0; j < 4; j++) {
                gll16(aS + j * 32768 + k0, dA + j * 2048 + ldst);
                gll16(bS + j * 32768 + k0, dB + j * 2048 + ldst);
            }
        }
        const u16* Ab = lbase + buf * 16384;
        const u16* Bb = Ab + 8192;
        u16x8 a0[4], a1[4], b0[4], b1[4];
        #pragma unroll
        for (int i = 0; i < 4; i++) {
            a0[i] = *(const u16x8*)&Ab[(wm + i * 16 + lane16) * 64 + cko0];
            a1[i] = *(const u16x8*)&Ab[(wm + i * 16 + lane16) * 64 + cko1];
            b0[i] = *(const u16x8*)&Bb[(wn + i * 16 + lane16) * 64 + cko0];
            b1[i] = *(const u16x8*)&Bb[(wn + i * 16 + lane16) * 64 + cko1];
        }
        #pragma unroll
        for (int am = 0; am < 4; am++)
            #pragma unroll
            for (int bn = 0; bn < 4; bn++)
                acc[am][bn] = __builtin_amdgcn_mfma_f32_16x16x32_bf16(
                    __builtin_bit_cast(bf16x8, a0[am]),
                    __builtin_bit_cast(bf16x8, b0[bn]), acc[am][bn], 0, 0, 0);
        #pragma unroll
        for (int am = 0; am < 4; am++)
            #pragma unroll
            for (int bn = 0; bn < 4; bn++)
                acc[am][bn] = __builtin_amdgcn_mfma_f32_16x16x32_bf16(
                    __builtin_bit_cast(bf16x8, a1[am]),
                    __builtin_bit_cast(bf16x8, b1[bn]), acc[am][bn], 0, 0, 0);
        __syncthreads();                       // drains next-tile glls + sync
        buf ^= 1;
    }

    const float* bcol = bias + (qblk ? 0 : 1024) + colBase;
    u16* Cb; int colLoc;
    if (qblk)        { Cb = Qo; colLoc = colBase; }
    else if (nx < 8) { Cb = Ko; colLoc = colBase; }
    else             { Cb = Vo; colLoc = colBase - 1024; }
    #pragma unroll
    for (int am = 0; am < 4; am++)
        #pragma unroll
        for (int bn = 0; bn < 4; bn++)
            #pragma unroll
            for (int r = 0; r < 4; r++) {
                int row = rowBase + wm + am * 16 + quad * 4 + r;
                int col = wn + bn * 16 + lane16;
                float v = acc[am][bn][r] + bcol[col];
                Cb[(long long)row * 1024 + colLoc + col] = f2bf(v);
            }
}

// ---------------------------------------------------------------------------
// Out-projection: same pipelined structure, 128x128 tile, split-K=2.
// 256 blocks (16 my x 8 nx x 2 kh), fp32 partials; ln sums them.
// ---------------------------------------------------------------------------
__global__ __launch_bounds__(256) void gemm_out(const u16* __restrict__ ctx,
                                                const u16* __restrict__ wob,
                                                const float* __restrict__ bias,
                                                float* __restrict__ ao0,
                                                float* __restrict__ ao1) {
    __shared__ u16 lds[2][2][8192];
    const int tid = threadIdx.x;
    const int wave = tid >> 6, lane = tid & 63;
    const int lane16 = lane & 15, quad = lane >> 4;
    const int bid = blockIdx.x;
    const int g = (bid & 7) * 32 + (bid >> 3);        // 256%8==0
    const int my = g >> 4;
    const int nx = (g & 15) >> 1;
    const int kh = g & 1;
    const int rowBase = my * 128, colBase = nx * 128, kbase = kh * 512;
    const int wm = (wave >> 1) * 64, wn = (wave & 1) * 64;

    floatx4 acc[4][4];
    #pragma unroll
    for (int am = 0; am < 4; am++)
        #pragma unroll
        for (int bn = 0; bn < 4; bn++) acc[am][bn] = floatx4{0.f, 0.f, 0.f, 0.f};

    const int srow8 = tid >> 3;
    const int scol = ((tid & 7) ^ (srow8 & 7)) * 8;
    const u16* aS = ctx + (long long)(rowBase + srow8) * 1024 + kbase + scol;
    const u16* bS = wob + (long long)(colBase + srow8) * 1024 + kbase + scol;
    u16* lbase = &lds[0][0][0];
    const int ldst = wave * 512;
    const int cko0 = ((quad ^ (lane16 & 7)) * 8);
    const int cko1 = (((4 + quad) ^ (lane16 & 7)) * 8);

    {
        u16* dA = lbase; u16* dB = lbase + 8192;
        #pragma unroll
        for (int j = 0; j < 4; j++) {
            gll16(aS + j * 32768, dA + j * 2048 + ldst);
            gll16(bS + j * 32768, dB + j * 2048 + ldst);
        }
    }
    __syncthreads();

    int buf = 0;
    for (int t = 0; t < 8; t++) {
        if (t < 7) {
            const int k0 = (t + 1) * 64;
            u16* dA = lbase + (buf ^ 1) * 16384;
            u16* dB = dA + 8192;
            #pragma unroll
            for (int j = 0; j < 4; j++) {
                gll16(aS + j * 32768 + k0, dA + j * 2048 + ldst);
                gll16(bS + j * 32768 + k0, dB + j * 2048 + ldst);
            }
        }
        const u16* Ab = lbase + buf * 16384;
        const u16* Bb = Ab + 8192;
        u16x8 a0[4], a1[4], b0[4], b1[4];
        #pragma unroll
        for (int i = 0; i < 4; i++) {
            a0[i] = *(const u16x8*)&Ab[(wm + i * 16 + lane16) * 64 + cko0];
            a1[i] = *(const u16x8*)&Ab[(wm + i * 16 + lane16) * 64 + cko1];
            b0[i] = *(const u16x8*)&Bb[(wn + i * 16 + lane16) * 64 + cko0];
            b1[i] = *(const u16x8*)&Bb[(wn + i * 16 + lane16) * 64 + cko1];
        }
        #pragma unroll
        for (int am = 0; am < 4; am++)
            #pragma unroll
            for (int bn = 0; bn < 4; bn++)
                acc[am][bn] = __builtin_amdgcn_mfma_f32_16x16x32_bf16(
                    __builtin_bit_cast(bf16x8, a0[am]),
                    __builtin_bit_cast(bf16x8, b0[bn]), acc[am][bn], 0, 0, 0);
        #pragma unroll
        for (int am = 0; am < 4; am++)
            #pragma unroll
            for (int bn = 0; bn < 4; bn++)
                acc[am][bn] = __builtin_amdgcn_mfma_f32_16x16x32_bf16(
                    __builtin_bit_cast(bf16x8, a1[am]),
                    __builtin_bit_cast(bf16x8, b1[bn]), acc[am][bn], 0, 0, 0);
        __syncthreads();
        buf ^= 1;
    }

    float* Co = kh ? ao1 : ao0;
    #pragma unroll
    for (int am = 0; am < 4; am++)
        #pragma unroll
        for (int bn = 0; bn < 4; bn++)
            #pragma unroll
            for (int r = 0; r < 4; r++) {
                int row = rowBase + wm + am * 16 + quad * 4 + r;
                int col = colBase + wn + bn * 16 + lane16;
                float v = acc[am][bn][r] + (kh == 0 ? bias[col] : 0.f);
                Co[(long long)row * 1024 + col] = v;
            }
}

// ---------------------------------------------------------------------------
// MFMA flash attention, 3-way key-segment split. (verbatim, passed R1/R2)
// ---------------------------------------------------------------------------
__global__ __launch_bounds__(256) void attn_seg(const u16* __restrict__ Q,
                                                const u16* __restrict__ Kb,
                                                const u16* __restrict__ Vb,
                                                float* __restrict__ pO_lo,
                                                float* __restrict__ pO_hi,
                                                float* __restrict__ pml) {
    __shared__ u16 Vt[2][64 * 80];
    __shared__ u16 Ps[4][16 * 80];
    const int tid = threadIdx.x;
    const int wave = tid >> 6, lane = tid & 63;
    const int lane16 = lane & 15, quad = lane >> 4;
    const int idx_ = blockIdx.x;                 // seg*512 + b*256 + h*16 + qhat
    const int qhat = idx_ & 15;
    const int h   = (idx_ >> 4) & 15;
    const int b   = (idx_ >> 8) & 1;
    const int seg = idx_ >> 9;
    const int qt = b ? (15 - qhat) : qhat;
    const int l0 = qt * 64;
    const int wq = wave * 16;
    const float scale = 0.125f;

    bf16x8 qf[2];
    {
        const u16* qrow = Q + ((long long)(b * 1024 + l0 + wq + lane16)) * 1024 + h * 64;
        qf[0] = __builtin_bit_cast(bf16x8, *(const u16x8*)(qrow + quad * 8));
        qf[1] = __builtin_bit_cast(bf16x8, *(const u16x8*)(qrow + 32 + quad * 8));
    }

    const int skey = tid >> 2, sdb = (tid & 3) * 16;
    const long long bh = ((long long)b * 3072) * 1024 + h * 64;

    u16x8 kr[8], vr0, vr1;
    {
        long long o = bh + ((long long)(seg * 1024)) * 1024;
        vr0 = *(const u16x8*)(Vb + o + (long long)skey * 1024 + sdb);
        vr1 = *(const u16x8*)(Vb + o + (long long)skey * 1024 + sdb + 8);
        #pragma unroll
        for (int c = 0; c < 2; c++)
            #pragma unroll
            for (int mi = 0; mi < 4; mi++)
                kr[c * 4 + mi] = *(const u16x8*)(Kb + o + (long long)(mi * 16 + lane16) * 1024 + c * 32 + quad * 8);
    }
    #pragma unroll
    for (int i = 0; i < 8; i++) {
        Vt[0][(sdb + i) * 80 + skey]     = vr0[i];
        Vt[0][(sdb + 8 + i) * 80 + skey] = vr1[i];
    }
    __syncthreads();

    float m_i = -1e30f, l_i = 0.f;
    floatx4 o_acc[4];
    #pragma unroll
    for (int mi = 0; mi < 4; mi++) o_acc[mi] = floatx4{0.f, 0.f, 0.f, 0.f};

    for (int t = 0; t <= qt; t++) {
        const int cur = t & 1;
        const bool haveNext = t < qt;

        u16x8 nkr[8], nvr0, nvr1;
        if (haveNext) {
            long long o = bh + ((long long)(seg * 1024 + (t + 1) * 64)) * 1024;
            nvr0 = *(const u16x8*)(Vb + o + (long long)skey * 1024 + sdb);
            nvr1 = *(const u16x8*)(Vb + o + (long long)skey * 1024 + sdb + 8);
            #pragma unroll
            for (int c = 0; c < 2; c++)
                #pragma unroll
                for (int mi = 0; mi < 4; mi++)
                    nkr[c * 4 + mi] = *(const u16x8*)(Kb + o + (long long)(mi * 16 + lane16) * 1024 + c * 32 + quad * 8);
        }

        floatx4 sacc[4];
        #pragma unroll
        for (int mi = 0; mi < 4; mi++) sacc[mi] = floatx4{0.f, 0.f, 0.f, 0.f};
        #pragma unroll
        for (int c = 0; c < 2; c++)
            #pragma unroll
            for (int mi = 0; mi < 4; mi++)
                sacc[mi] = __builtin_amdgcn_mfma_f32_16x16x32_bf16(
                    __builtin_bit_cast(bf16x8, kr[c * 4 + mi]), qf[c], sacc[mi], 0, 0, 0);

        const bool diag = (t == qt);
        const int qloc = wq + lane16;
        float tmax = -1e30f;
        #pragma unroll
        for (int mi = 0; mi < 4; mi++)
            #pragma unroll
            for (int r = 0; r < 4; r++) {
                float s = sacc[mi][r] * scale;
                if (diag && (mi * 16 + quad * 4 + r) > qloc) s = -1e30f;
                sacc[mi][r] = s;
                tmax = fmaxf(tmax, s);
            }
        tmax = fmaxf(tmax, __shfl_xor(tmax, 16));
        tmax = fmaxf(tmax, __shfl_xor(tmax, 32));
        float m_new = fmaxf(m_i, tmax);
        float alpha = __expf(m_i - m_new);
        float psum = 0.f;
        #pragma unroll
        for (int mi = 0; mi < 4; mi++)
            #pragma unroll
            for (int r = 0; r < 4; r++) {
                float p = __expf(sacc[mi][r] - m_new);
                psum += p;
                Ps[wave][lane16 * 80 + mi * 16 + quad * 4 + r] = f2bf(p);
            }
        psum += __shfl_xor(psum, 16);
        psum += __shfl_xor(psum, 32);
        m_i = m_new;
        l_i = l_i * alpha + psum;
        #pragma unroll
        for (int mi = 0; mi < 4; mi++)
            #pragma unroll
            for (int r = 0; r < 4; r++) o_acc[mi][r] *= alpha;

        __builtin_amdgcn_wave_barrier();

        #pragma unroll
        for (int c = 0; c < 2; c++) {
            bf16x8 pf = __builtin_bit_cast(bf16x8,
                *(const u16x8*)&Ps[wave][lane16 * 80 + c * 32 + quad * 8]);
            #pragma unroll
            for (int mi = 0; mi < 4; mi++) {
                bf16x8 vf = __builtin_bit_cast(bf16x8,
                    *(const u16x8*)&Vt[cur][(mi * 16 + lane16) * 80 + c * 32 + quad * 8]);
                o_acc[mi] = __builtin_amdgcn_mfma_f32_16x16x32_bf16(vf, pf, o_acc[mi], 0, 0, 0);
            }
        }

        if (haveNext) {
            #pragma unroll
            for (int i = 0; i < 8; i++) {
                Vt[cur ^ 1][(sdb + i) * 80 + skey]     = nvr0[i];
                Vt[cur ^ 1][(sdb + 8 + i) * 80 + skey] = nvr1[i];
            }
            #pragma unroll
            for (int i = 0; i < 8; i++) kr[i] = nkr[i];
            __syncthreads();
        }
    }

    const int p = ((b * 16 + h) * 16 + qt) * 3 + seg;     // 0..1535
    float* op = (p < 512) ? (pO_lo + (long long)p * 4096)
                          : (pO_hi + (long long)(p - 512) * 4096);
    if (quad == 0) {
        pml[(long long)p * 128 + (wq + lane16) * 2]     = m_i;
        pml[(long long)p * 128 + (wq + lane16) * 2 + 1] = l_i;
    }
    float* orow = op + (long long)(wq + lane16) * 64;
    #pragma unroll
    for (int mi = 0; mi < 4; mi++)
        *(floatx4*)(orow + mi * 16 + quad * 4) = o_acc[mi];
}

// ---------------------------------------------------------------------------
// Merge the 3 segment-partials per (b,h,qt). (verbatim, passed R1/R2)
// ---------------------------------------------------------------------------
__global__ __launch_bounds__(256) void attn_combine(const float* __restrict__ pO_lo,
                                                    const float* __restrict__ pO_hi,
                                                    const float* __restrict__ pml,
                                                    u16* __restrict__ Ctx) {
    const int g = blockIdx.x;            // b*256 + h*16 + qt
    const int qt = g & 15;
    const int h  = (g >> 4) & 15;
    const int b  = g >> 8;
    const int t  = threadIdx.x;
    const int q  = t >> 2;
    const int d0 = (t & 3) * 16;
    const int p0 = g * 3;

    float m[3], l[3];
    #pragma unroll
    for (int s = 0; s < 3; s++) {
        m[s] = pml[(long long)(p0 + s) * 128 + q * 2];
        l[s] = pml[(long long)(p0 + s) * 128 + q * 2 + 1];
    }
    float M = fmaxf(m[0], fmaxf(m[1], m[2]));
    float w[3];
    #pragma unroll
    for (int s = 0; s < 3; s++) w[s] = __expf(m[s] - M);
    float L = w[0] * l[0] + w[1] * l[1] + w[2] * l[2];
    float invL = 1.0f / L;

    const float* O[3];
    #pragma unroll
    for (int s = 0; s < 3; s++) {
        int pp = p0 + s;
        O[s] = ((pp < 512) ? (pO_lo + (long long)pp * 4096)
                           : (pO_hi + (long long)(pp - 512) * 4096))
               + (long long)q * 64 + d0;
    }

    long long crow = ((long long)(b * 1024 + qt * 64 + q)) * 1024 + h * 64 + d0;
    #pragma unroll
    for (int i = 0; i < 16; i += 4) {
        floatx4 a  = *(const floatx4*)(O[0] + i);
        floatx4 bb = *(const floatx4*)(O[1] + i);
        floatx4 cc = *(const floatx4*)(O[2] + i);
        #pragma unroll
        for (int j = 0; j < 4; j++)
            Ctx[crow + i + j] = f2bf((w[0] * a[j] + w[1] * bb[j] + w[2] * cc[j]) * invL);
    }
}

// ---------------------------------------------------------------------------
// residual + LayerNorm + mask; sums the two split-K out-proj partials.
// ---------------------------------------------------------------------------
__global__ __launch_bounds__(256) void ln_kernel(const float* __restrict__ AO0,
                                                 const float* __restrict__ AO1,
                                                 const float* __restrict__ HQ,
                                                 const float* __restrict__ g,
                                                 const float* __restrict__ bb,
                                                 const float* __restrict__ mask,
                                                 float* __restrict__ Out) {
    const int row = blockIdx.x;
    const int t = threadIdx.x;
    const int base = row * 1024 + t * 4;
    floatx4 a0 = *(const floatx4*)&AO0[base];
    floatx4 a1 = *(const floatx4*)&AO1[base];
    floatx4 hq = *(const floatx4*)&HQ[base];
    float x[4];
    #pragma unroll
    for (int i = 0; i < 4; i++) x[i] = a0[i] + a1[i] + hq[i];
    float s = x[0] + x[1] + x[2] + x[3];
    float ss = x[0]*x[0] + x[1]*x[1] + x[2]*x[2] + x[3]*x[3];
    #pragma unroll
    for (int off = 32; off >= 1; off >>= 1) { s += __shfl_xor(s, off); ss += __shfl_xor(ss, off); }
    __shared__ float smem[8];
    int wave = t >> 6, lane = t & 63;
    if (lane == 0) { smem[wave] = s; smem[4 + wave] = ss; }
    __syncthreads();
    s  = smem[0] + smem[1] + smem[2] + smem[3];
    ss = smem[4] + smem[5] + smem[6] + smem[7];
    float mu  = s * (1.f / 1024.f);
    float var = ss * (1.f / 1024.f) - mu * mu;
    float rs  = rsqrtf(var + 1e-5f);
    float mv  = mask[row];
    floatx4 g4 = *(const floatx4*)&g[t * 4];
    floatx4 b4 = *(const floatx4*)&bb[t * 4];
    floatx4 y4;
    #pragma unroll
    for (int i = 0; i < 4; i++) y4[i] = ((x[i] - mu) * rs * g4[i] + b4[i]) * mv;
    *(floatx4*)&Out[base] = y4;
}

// ---------------------------------------------------------------------------
// Workspace map (high-water 44.75 MB, proven safe):
//   ws+0      q_b  4 MB  (-> ctx bf16 in place after combine)
//   ws+4 MB   k_b 12 MB  (dead after attn -> ao0 fp32 8 MB at ws+4)
//   ws+12 MB  (ao1 fp32 8 MB at ws+12, over k_b tail / v_b head, both dead)
//   ws+16 MB  v_b 12 MB
//   ws+28 MB  a_q 4 MB + a_kv 12 MB (cvt->proj; dead after)
//             -> pO_hi 16 MB (attn->combine; dead after)
//             -> wob 2 MB (cvt after combine -> gemm_out)
//   ws+44 MB  pml 0.75 MB
//   d_out 8 MB: wb bf16 6 MB (cvt->proj) -> pO_lo (attn->combine) -> output.
// ---------------------------------------------------------------------------
extern "C" void kernel_launch(void* const* d_in, const int* in_sizes, int n_in,
                              void* d_out, int out_size, void* d_ws, size_t ws_size,
                              hipStream_t stream) {
    (void)in_sizes; (void)n_in; (void)out_size; (void)ws_size;
    const float* h_q   = (const float*)d_in[0];
    const float* h_kv1 = (const float*)d_in[1];
    const float* h_kv2 = (const float*)d_in[2];
    const float* maskp = (const float*)d_in[3];
    const float* win   = (const float*)d_in[4];
    const float* binp  = (const float*)d_in[5];
    const float* wout  = (const float*)d_in[6];
    const float* bout  = (const float*)d_in[7];
    const float* ln_g  = (const float*)d_in[8];
    const float* ln_b  = (const float*)d_in[9];
    float* outp = (float*)d_out;

    char* ws = (char*)d_ws;
    const size_t MB = 1024 * 1024;
    u16*   q_b   = (u16*)(ws);
    u16*   k_b   = (u16*)(ws + 4 * MB);
    u16*   v_b   = (u16*)(ws + 16 * MB);
    u16*   ctx_b = q_b;
    u16*   a_q   = (u16*)(ws + 28 * MB);
    u16*   a_kv  = (u16*)(ws + 32 * MB);
    u16*   wb    = (u16*)d_out;                // scratch until attn
    float* pO_lo = (float*)d_out;
    float* pO_hi = (float*)(ws + 28 * MB);
    u16*   wob   = (u16*)(ws + 28 * MB);       // after combine
    float* pml   = (float*)(ws + 44 * MB);
    float* ao0   = (float*)(ws + 4 * MB);
    float* ao1   = (float*)(ws + 12 * MB);

    cvt_all<<<2048, 256, 0, stream>>>(h_q, h_kv1, h_kv2, win, a_q, a_kv, wb);
    gemm_proj<<<896, 256, 0, stream>>>(a_q, a_kv, wb, binp, q_b, k_b, v_b);
    attn_seg<<<1536, 256, 0, stream>>>(q_b, k_b, v_b, pO_lo, pO_hi, pml);
    attn_combine<<<512, 256, 0, stream>>>(pO_lo, pO_hi, pml, ctx_b);
    cvt_bf16<<<512, 256, 0, stream>>>(wout, wob, 131072);
    gemm_out<<<256, 256, 0, stream>>>(ctx_b, wob, bout, ao0, ao1);
    ln_kernel<<<2048, 256, 0, stream>>>(ao0, ao1, h_q, ln_g, ln_b, maskp, outp);
}

// Round 5
// 225.779 us; speedup vs baseline: 1.3481x; 1.0703x over previous
//
#include <hip/hip_runtime.h>
#include <stdint.h>

typedef unsigned short u16;
typedef unsigned int u32;
typedef __bf16 bf16x8 __attribute__((ext_vector_type(8)));
typedef float floatx4 __attribute__((ext_vector_type(4)));
typedef u16 u16x8 __attribute__((ext_vector_type(8)));
typedef u16 u16x4 __attribute__((ext_vector_type(4)));

__device__ __forceinline__ u16 f2bf(float f) {
    __bf16 h = (__bf16)f;
    return __builtin_bit_cast(u16, h);
}

// async global->LDS, 16B per lane. LDS dest = wave-uniform base + lane*16.
__device__ __forceinline__ void gll16(const u16* g, u16* l) {
    typedef __attribute__((address_space(1))) u32 gu32;
    typedef __attribute__((address_space(3))) u32 lu32;
    __builtin_amdgcn_global_load_lds((gu32*)g, (lu32*)l, 16, 0, 0);
}

// ---------------------------------------------------------------------------
// One-shot fp32->bf16 convert of h_q, concat(kv1,kv2), and W_in. (unchanged)
// ---------------------------------------------------------------------------
__global__ __launch_bounds__(256) void cvt_all(const float* __restrict__ hq,
                                               const float* __restrict__ kv1,
                                               const float* __restrict__ kv2,
                                               const float* __restrict__ win,
                                               u16* __restrict__ a_q,
                                               u16* __restrict__ a_kv,
                                               u16* __restrict__ wb) {
    const int NQ = 262144, NKV = 786432, NW = 393216;   // 8-elem chunks
    int i = blockIdx.x * 256 + threadIdx.x;
    const int stride = gridDim.x * 256;
    for (; i < NQ + NKV + NW; i += stride) {
        const float* src; u16* dst;
        if (i < NQ) {
            src = hq + (long long)i * 8; dst = a_q + (long long)i * 8;
        } else if (i < NQ + NKV) {
            int c = i - NQ;
            int row = c >> 7;                 // 128 chunks per 1024-elem row
            int col = (c & 127) * 8;
            int b = row >= 3072, r = row - b * 3072;
            src = (r < 1024) ? kv1 + ((long long)(b * 1024 + r)) * 1024 + col
                             : kv2 + ((long long)(b * 2048 + (r - 1024))) * 1024 + col;
            dst = a_kv + (long long)row * 1024 + col;
        } else {
            int c = i - (NQ + NKV);
            src = win + (long long)c * 8; dst = wb + (long long)c * 8;
        }
        floatx4 x = *(const floatx4*)src;
        floatx4 y = *(const floatx4*)(src + 4);
        u16x8 o;
        #pragma unroll
        for (int j = 0; j < 4; j++) { o[j] = f2bf(x[j]); o[4 + j] = f2bf(y[j]); }
        *(u16x8*)dst = o;
    }
}

// plain fp32->bf16 flat convert (for W_out, launched after combine)
__global__ __launch_bounds__(256) void cvt_bf16(const float* __restrict__ in,
                                                u16* __restrict__ out, int n8) {
    int i = blockIdx.x * 256 + threadIdx.x;
    const int stride = gridDim.x * 256;
    for (; i < n8; i += stride) {
        floatx4 a = *(const floatx4*)(in + (long long)i * 8);
        floatx4 b = *(const floatx4*)(in + (long long)i * 8 + 4);
        u16x8 o;
        #pragma unroll
        for (int j = 0; j < 4; j++) { o[j] = f2bf(a[j]); o[4 + j] = f2bf(b[j]); }
        *(u16x8*)(out + (long long)i * 8) = o;
    }
}

// ---------------------------------------------------------------------------
// Fused Q+K+V projection (structure verified in R4). ONE change: V output is
// written TRANSPOSED vT[b][d][key] (packed u16x4 over the 4 consecutive keys
// each lane owns) so attention can stage V via global_load_lds in its
// consumed [d][key] layout.
// ---------------------------------------------------------------------------
__global__ __launch_bounds__(256) void gemm_proj(const u16* __restrict__ aq,
                                                 const u16* __restrict__ akv,
                                                 const u16* __restrict__ wb,
                                                 const float* __restrict__ bias,
                                                 u16* __restrict__ Qo,
                                                 u16* __restrict__ Ko,
                                                 u16* __restrict__ VTg) {
    __shared__ u16 lds[2][2][8192];            // [buf][A|B][128 rows x 64 cols]
    const int tid = threadIdx.x;
    const int wave = tid >> 6, lane = tid & 63;
    const int lane16 = lane & 15, quad = lane >> 4;
    const int bid = blockIdx.x;
    const int g = (bid & 7) * 112 + (bid >> 3);   // XCD swizzle, 896%8==0
    const bool qblk = g < 128;
    int my, nx;
    if (qblk) { my = g >> 3; nx = g & 7; }            // 16 x 8
    else { int gg = g - 128; my = gg >> 4; nx = gg & 15; }  // 48 x 16
    const int rowBase = my * 128;
    const int colBase = nx * 128;
    const int wrow = (qblk ? 0 : 1024) + colBase;
    const int wm = (wave >> 1) * 64, wn = (wave & 1) * 64;

    floatx4 acc[4][4];
    #pragma unroll
    for (int am = 0; am < 4; am++)
        #pragma unroll
        for (int bn = 0; bn < 4; bn++) acc[am][bn] = floatx4{0.f, 0.f, 0.f, 0.f};

    const int srow8 = tid >> 3;
    const int scol = ((tid & 7) ^ (srow8 & 7)) * 8;
    const u16* aS = (qblk ? aq : akv) + (long long)(rowBase + srow8) * 1024 + scol;
    const u16* bS = wb + (long long)(wrow + srow8) * 1024 + scol;
    u16* lbase = &lds[0][0][0];
    const int ldst = wave * 512;               // u16; HW adds lane*16 B

    const int cko0 = ((quad ^ (lane16 & 7)) * 8);        // k-half 0
    const int cko1 = (((4 + quad) ^ (lane16 & 7)) * 8);  // k-half 1

    {   // prologue: stage tile 0 into buf 0
        u16* dA = lbase; u16* dB = lbase + 8192;
        #pragma unroll
        for (int j = 0; j < 4; j++) {
            gll16(aS + j * 32768, dA + j * 2048 + ldst);
            gll16(bS + j * 32768, dB + j * 2048 + ldst);
        }
    }
    __syncthreads();

    int buf = 0;
    for (int t = 0; t < 16; t++) {
        if (t < 15) {                          // issue next tile FIRST
            const int k0 = (t + 1) * 64;
            u16* dA = lbase + (buf ^ 1) * 16384;
            u16* dB = dA + 8192;
            #pragma unroll
            for (int j = 0; j < 4; j++) {
                gll16(aS + j * 32768 + k0, dA + j * 2048 + ldst);
                gll16(bS + j * 32768 + k0, dB + j * 2048 + ldst);
            }
        }
        const u16* Ab = lbase + buf * 16384;
        const u16* Bb = Ab + 8192;
        u16x8 a0[4], a1[4], b0[4], b1[4];
        #pragma unroll
        for (int i = 0; i < 4; i++) {
            a0[i] = *(const u16x8*)&Ab[(wm + i * 16 + lane16) * 64 + cko0];
            a1[i] = *(const u16x8*)&Ab[(wm + i * 16 + lane16) * 64 + cko1];
            b0[i] = *(const u16x8*)&Bb[(wn + i * 16 + lane16) * 64 + cko0];
            b1[i] = *(const u16x8*)&Bb[(wn + i * 16 + lane16) * 64 + cko1];
        }
        #pragma unroll
        for (int am = 0; am < 4; am++)
            #pragma unroll
            for (int bn = 0; bn < 4; bn++)
                acc[am][bn] = __builtin_amdgcn_mfma_f32_16x16x32_bf16(
                    __builtin_bit_cast(bf16x8, a0[am]),
                    __builtin_bit_cast(bf16x8, b0[bn]), acc[am][bn], 0, 0, 0);
        #pragma unroll
        for (int am = 0; am < 4; am++)
            #pragma unroll
            for (int bn = 0; bn < 4; bn++)
                acc[am][bn] = __builtin_amdgcn_mfma_f32_16x16x32_bf16(
                    __builtin_bit_cast(bf16x8, a1[am]),
                    __builtin_bit_cast(bf16x8, b1[bn]), acc[am][bn], 0, 0, 0);
        __syncthreads();                       // drains next-tile glls + sync
        buf ^= 1;
    }

    const float* bcol = bias + (qblk ? 0 : 1024) + colBase;
    if (qblk || nx < 8) {                      // Q / K: natural [row][d] bf16
        u16* Cb = qblk ? Qo : Ko;
        #pragma unroll
        for (int am = 0; am < 4; am++)
            #pragma unroll
            for (int bn = 0; bn < 4; bn++)
                #pragma unroll
                for (int r = 0; r < 4; r++) {
                    int row = rowBase + wm + am * 16 + quad * 4 + r;
                    int col = wn + bn * 16 + lane16;
                    float v = acc[am][bn][r] + bcol[col];
                    Cb[(long long)row * 1024 + colBase + col] = f2bf(v);
                }
    } else {                                   // V: transposed vT[b][d][key]
        const int b_ = rowBase >= 3072;
        const int keyBase = rowBase - b_ * 3072 + wm;
        #pragma unroll
        for (int am = 0; am < 4; am++)
            #pragma unroll
            for (int bn = 0; bn < 4; bn++) {
                int col = wn + bn * 16 + lane16;
                int d = colBase - 1024 + col;
                int key0 = keyBase + am * 16 + quad * 4;
                u16x4 pk;
                #pragma unroll
                for (int r = 0; r < 4; r++) pk[r] = f2bf(acc[am][bn][r] + bcol[col]);
                *(u16x4*)&VTg[((long long)(b_ * 1024 + d)) * 3072 + key0] = pk;
            }
    }
}

// ---------------------------------------------------------------------------
// Out-projection (verified R4, unchanged). 128x128 tile, split-K=2.
// ---------------------------------------------------------------------------
__global__ __launch_bounds__(256) void gemm_out(const u16* __restrict__ ctx,
                                                const u16* __restrict__ wob,
                                                const float* __restrict__ bias,
                                                float* __restrict__ ao0,
                                                float* __restrict__ ao1) {
    __shared__ u16 lds[2][2][8192];
    const int tid = threadIdx.x;
    const int wave = tid >> 6, lane = tid & 63;
    const int lane16 = lane & 15, quad = lane >> 4;
    const int bid = blockIdx.x;
    const int g = (bid & 7) * 32 + (bid >> 3);        // 256%8==0
    const int my = g >> 4;
    const int nx = (g & 15) >> 1;
    const int kh = g & 1;
    const int rowBase = my * 128, colBase = nx * 128, kbase = kh * 512;
    const int wm = (wave >> 1) * 64, wn = (wave & 1) * 64;

    floatx4 acc[4][4];
    #pragma unroll
    for (int am = 0; am < 4; am++)
        #pragma unroll
        for (int bn = 0; bn < 4; bn++) acc[am][bn] = floatx4{0.f, 0.f, 0.f, 0.f};

    const int srow8 = tid >> 3;
    const int scol = ((tid & 7) ^ (srow8 & 7)) * 8;
    const u16* aS = ctx + (long long)(rowBase + srow8) * 1024 + kbase + scol;
    const u16* bS = wob + (long long)(colBase + srow8) * 1024 + kbase + scol;
    u16* lbase = &lds[0][0][0];
    const int ldst = wave * 512;
    const int cko0 = ((quad ^ (lane16 & 7)) * 8);
    const int cko1 = (((4 + quad) ^ (lane16 & 7)) * 8);

    {
        u16* dA = lbase; u16* dB = lbase + 8192;
        #pragma unroll
        for (int j = 0; j < 4; j++) {
            gll16(aS + j * 32768, dA + j * 2048 + ldst);
            gll16(bS + j * 32768, dB + j * 2048 + ldst);
        }
    }
    __syncthreads();

    int buf = 0;
    for (int t = 0; t < 8; t++) {
        if (t < 7) {
            const int k0 = (t + 1) * 64;
            u16* dA = lbase + (buf ^ 1) * 16384;
            u16* dB = dA + 8192;
            #pragma unroll
            for (int j = 0; j < 4; j++) {
                gll16(aS + j * 32768 + k0, dA + j * 2048 + ldst);
                gll16(bS + j * 32768 + k0, dB + j * 2048 + ldst);
            }
        }
        const u16* Ab = lbase + buf * 16384;
        const u16* Bb = Ab + 8192;
        u16x8 a0[4], a1[4], b0[4], b1[4];
        #pragma unroll
        for (int i = 0; i < 4; i++) {
            a0[i] = *(const u16x8*)&Ab[(wm + i * 16 + lane16) * 64 + cko0];
            a1[i] = *(const u16x8*)&Ab[(wm + i * 16 + lane16) * 64 + cko1];
            b0[i] = *(const u16x8*)&Bb[(wn + i * 16 + lane16) * 64 + cko0];
            b1[i] = *(const u16x8*)&Bb[(wn + i * 16 + lane16) * 64 + cko1];
        }
        #pragma unroll
        for (int am = 0; am < 4; am++)
            #pragma unroll
            for (int bn = 0; bn < 4; bn++)
                acc[am][bn] = __builtin_amdgcn_mfma_f32_16x16x32_bf16(
                    __builtin_bit_cast(bf16x8, a0[am]),
                    __builtin_bit_cast(bf16x8, b0[bn]), acc[am][bn], 0, 0, 0);
        #pragma unroll
        for (int am = 0; am < 4; am++)
            #pragma unroll
            for (int bn = 0; bn < 4; bn++)
                acc[am][bn] = __builtin_amdgcn_mfma_f32_16x16x32_bf16(
                    __builtin_bit_cast(bf16x8, a1[am]),
                    __builtin_bit_cast(bf16x8, b1[bn]), acc[am][bn], 0, 0, 0);
        __syncthreads();
        buf ^= 1;
    }

    float* Co = kh ? ao1 : ao0;
    #pragma unroll
    for (int am = 0; am < 4; am++)
        #pragma unroll
        for (int bn = 0; bn < 4; bn++)
            #pragma unroll
            for (int r = 0; r < 4; r++) {
                int row = rowBase + wm + am * 16 + quad * 4 + r;
                int col = colBase + wn + bn * 16 + lane16;
                float v = acc[am][bn][r] + (kh == 0 ? bias[col] : 0.f);
                Co[(long long)row * 1024 + col] = v;
            }
}

// ---------------------------------------------------------------------------
// MFMA flash attention v2: K and V^T tiles staged via global_load_lds into
// double-buffered XOR-swizzled LDS (zero VGPR payload, truly async — fixes
// the VGPR-72 serialized "prefetch" of v1). Math/partials identical to the
// verified kernel. V consumed as [d][key] from vT global.
// ---------------------------------------------------------------------------
__global__ __launch_bounds__(256) void attn_seg(const u16* __restrict__ Q,
                                                const u16* __restrict__ Kb,
                                                const u16* __restrict__ VTg,
                                                float* __restrict__ pO_lo,
                                                float* __restrict__ pO_hi,
                                                float* __restrict__ pml) {
    __shared__ u16 Kt[2][4096];        // [key 64][d 64], d-chunk XOR-swizzled
    __shared__ u16 Vt[2][4096];        // [d 64][key 64], key-chunk XOR-swizzled
    __shared__ u16 Ps[4][1280];        // per-wave P roundtrip, stride 80
    const int tid = threadIdx.x;
    const int wave = tid >> 6, lane = tid & 63;
    const int lane16 = lane & 15, quad = lane >> 4;
    const int bid = blockIdx.x;
    const int idx_ = (bid & 7) * 192 + (bid >> 3);   // XCD swizzle, 1536%8==0
    const int qhat = idx_ & 15;
    const int h   = (idx_ >> 4) & 15;
    const int b   = (idx_ >> 8) & 1;
    const int seg = idx_ >> 9;
    const int qt = b ? (15 - qhat) : qhat;
    const int l0 = qt * 64;
    const int wq = wave * 16;
    const float scale = 0.125f;

    bf16x8 qf[2];
    {
        const u16* qrow = Q + ((long long)(b * 1024 + l0 + wq + lane16)) * 1024 + h * 64;
        qf[0] = __builtin_bit_cast(bf16x8, *(const u16x8*)(qrow + quad * 8));
        qf[1] = __builtin_bit_cast(bf16x8, *(const u16x8*)(qrow + 32 + quad * 8));
    }

    // staging: thread covers row srow(+32j), 8-u16 chunk (tid&7), source
    // chunk XOR'd by row&7 (rule #21: linear dest + inverse-swizzled source).
    const int srow = tid >> 3;                       // 0..31
    const int csw8 = ((tid & 7) ^ (srow & 7)) * 8;
    const long long bh = ((long long)b * 3072) * 1024 + h * 64;
    const u16* kS = Kb + bh + ((long long)(seg * 1024)) * 1024
                    + (long long)srow * 1024 + csw8;             // +t*65536
    const u16* vS = VTg + ((long long)(b * 1024 + h * 64 + srow)) * 3072
                    + seg * 1024 + csw8;                          // +t*64
    const int ldst = wave * 512;                     // u16; HW adds lane*16B

    {   // prologue: tile 0 -> buf 0
        #pragma unroll
        for (int j = 0; j < 2; j++) {
            gll16(kS + j * 32768, &Kt[0][j * 2048 + ldst]);
            gll16(vS + (long long)j * 32 * 3072, &Vt[0][j * 2048 + ldst]);
        }
    }
    __syncthreads();

    // fragment read slots: chunk (c*4+quad) ^ (row&7), row&7 == lane16&7
    const int slot0 = ((quad ^ (lane16 & 7)) * 8);
    const int slot1 = (((4 + quad) ^ (lane16 & 7)) * 8);

    float m_i = -1e30f, l_i = 0.f;
    floatx4 o_acc[4];
    #pragma unroll
    for (int mi = 0; mi < 4; mi++) o_acc[mi] = floatx4{0.f, 0.f, 0.f, 0.f};

    for (int t = 0; t <= qt; t++) {
        const int cur = t & 1;
        const bool haveNext = t < qt;

        if (haveNext) {                     // async stage next tile (no VGPRs)
            const long long ko = (long long)(t + 1) * 65536;
            const long long vo = (long long)(t + 1) * 64;
            #pragma unroll
            for (int j = 0; j < 2; j++) {
                gll16(kS + ko + j * 32768, &Kt[cur ^ 1][j * 2048 + ldst]);
                gll16(vS + vo + (long long)j * 32 * 3072, &Vt[cur ^ 1][j * 2048 + ldst]);
            }
        }

        // ---- QK^T ----
        floatx4 sacc[4];
        #pragma unroll
        for (int mi = 0; mi < 4; mi++) sacc[mi] = floatx4{0.f, 0.f, 0.f, 0.f};
        #pragma unroll
        for (int mi = 0; mi < 4; mi++) {
            u16x8 kf = *(const u16x8*)&Kt[cur][(mi * 16 + lane16) * 64 + slot0];
            sacc[mi] = __builtin_amdgcn_mfma_f32_16x16x32_bf16(
                __builtin_bit_cast(bf16x8, kf), qf[0], sacc[mi], 0, 0, 0);
        }
        #pragma unroll
        for (int mi = 0; mi < 4; mi++) {
            u16x8 kf = *(const u16x8*)&Kt[cur][(mi * 16 + lane16) * 64 + slot1];
            sacc[mi] = __builtin_amdgcn_mfma_f32_16x16x32_bf16(
                __builtin_bit_cast(bf16x8, kf), qf[1], sacc[mi], 0, 0, 0);
        }

        // ---- online softmax (identical math to verified kernel) ----
        const bool diag = (t == qt);
        const int qloc = wq + lane16;
        float tmax = -1e30f;
        #pragma unroll
        for (int mi = 0; mi < 4; mi++)
            #pragma unroll
            for (int r = 0; r < 4; r++) {
                float s = sacc[mi][r] * scale;
                if (diag && (mi * 16 + quad * 4 + r) > qloc) s = -1e30f;
                sacc[mi][r] = s;
                tmax = fmaxf(tmax, s);
            }
        tmax = fmaxf(tmax, __shfl_xor(tmax, 16));
        tmax = fmaxf(tmax, __shfl_xor(tmax, 32));
        float m_new = fmaxf(m_i, tmax);
        float alpha = __expf(m_i - m_new);
        float psum = 0.f;
        #pragma unroll
        for (int mi = 0; mi < 4; mi++) {
            u16x4 pk;
            #pragma unroll
            for (int r = 0; r < 4; r++) {
                float p = __expf(sacc[mi][r] - m_new);
                psum += p;
                pk[r] = f2bf(p);
            }
            *(u16x4*)&Ps[wave][lane16 * 80 + mi * 16 + quad * 4] = pk;
        }
        psum += __shfl_xor(psum, 16);
        psum += __shfl_xor(psum, 32);
        m_i = m_new;
        l_i = l_i * alpha + psum;
        #pragma unroll
        for (int mi = 0; mi < 4; mi++)
            #pragma unroll
            for (int r = 0; r < 4; r++) o_acc[mi][r] *= alpha;

        __builtin_amdgcn_wave_barrier();

        // ---- PV ----
        #pragma unroll
        for (int c = 0; c < 2; c++) {
            bf16x8 pf = __builtin_bit_cast(bf16x8,
                *(const u16x8*)&Ps[wave][lane16 * 80 + c * 32 + quad * 8]);
            const int slot = c ? slot1 : slot0;
            #pragma unroll
            for (int mi = 0; mi < 4; mi++) {
                bf16x8 vf = __builtin_bit_cast(bf16x8,
                    *(const u16x8*)&Vt[cur][(mi * 16 + lane16) * 64 + slot]);
                o_acc[mi] = __builtin_amdgcn_mfma_f32_16x16x32_bf16(vf, pf, o_acc[mi], 0, 0, 0);
            }
        }

        if (haveNext) __syncthreads();     // drains next-tile glls + buf swap
    }

    // ---- emit partials (unchanged) ----
    const int p = ((b * 16 + h) * 16 + qt) * 3 + seg;     // 0..1535
    float* op = (p < 512) ? (pO_lo + (long long)p * 4096)
                          : (pO_hi + (long long)(p - 512) * 4096);
    if (quad == 0) {
        pml[(long long)p * 128 + (wq + lane16) * 2]     = m_i;
        pml[(long long)p * 128 + (wq + lane16) * 2 + 1] = l_i;
    }
    float* orow = op + (long long)(wq + lane16) * 64;
    #pragma unroll
    for (int mi = 0; mi < 4; mi++)
        *(floatx4*)(orow + mi * 16 + quad * 4) = o_acc[mi];
}

// ---------------------------------------------------------------------------
// Merge the 3 segment-partials per (b,h,qt). (verbatim, passed R1/R2/R4)
// ---------------------------------------------------------------------------
__global__ __launch_bounds__(256) void attn_combine(const float* __restrict__ pO_lo,
                                                    const float* __restrict__ pO_hi,
                                                    const float* __restrict__ pml,
                                                    u16* __restrict__ Ctx) {
    const int g = blockIdx.x;            // b*256 + h*16 + qt
    const int qt = g & 15;
    const int h  = (g >> 4) & 15;
    const int b  = g >> 8;
    const int t  = threadIdx.x;
    const int q  = t >> 2;
    const int d0 = (t & 3) * 16;
    const int p0 = g * 3;

    float m[3], l[3];
    #pragma unroll
    for (int s = 0; s < 3; s++) {
        m[s] = pml[(long long)(p0 + s) * 128 + q * 2];
        l[s] = pml[(long long)(p0 + s) * 128 + q * 2 + 1];
    }
    float M = fmaxf(m[0], fmaxf(m[1], m[2]));
    float w[3];
    #pragma unroll
    for (int s = 0; s < 3; s++) w[s] = __expf(m[s] - M);
    float L = w[0] * l[0] + w[1] * l[1] + w[2] * l[2];
    float invL = 1.0f / L;

    const float* O[3];
    #pragma unroll
    for (int s = 0; s < 3; s++) {
        int pp = p0 + s;
        O[s] = ((pp < 512) ? (pO_lo + (long long)pp * 4096)
                           : (pO_hi + (long long)(pp - 512) * 4096))
               + (long long)q * 64 + d0;
    }

    long long crow = ((long long)(b * 1024 + qt * 64 + q)) * 1024 + h * 64 + d0;
    #pragma unroll
    for (int i = 0; i < 16; i += 4) {
        floatx4 a  = *(const floatx4*)(O[0] + i);
        floatx4 bb = *(const floatx4*)(O[1] + i);
        floatx4 cc = *(const floatx4*)(O[2] + i);
        #pragma unroll
        for (int j = 0; j < 4; j++)
            Ctx[crow + i + j] = f2bf((w[0] * a[j] + w[1] * bb[j] + w[2] * cc[j]) * invL);
    }
}

// ---------------------------------------------------------------------------
// residual + LayerNorm + mask; sums the two split-K out-proj partials.
// ---------------------------------------------------------------------------
__global__ __launch_bounds__(256) void ln_kernel(const float* __restrict__ AO0,
                                                 const float* __restrict__ AO1,
                                                 const float* __restrict__ HQ,
                                                 const float* __restrict__ g,
                                                 const float* __restrict__ bb,
                                                 const float* __restrict__ mask,
                                                 float* __restrict__ Out) {
    const int row = blockIdx.x;
    const int t = threadIdx.x;
    const int base = row * 1024 + t * 4;
    floatx4 a0 = *(const floatx4*)&AO0[base];
    floatx4 a1 = *(const floatx4*)&AO1[base];
    floatx4 hq = *(const floatx4*)&HQ[base];
    float x[4];
    #pragma unroll
    for (int i = 0; i < 4; i++) x[i] = a0[i] + a1[i] + hq[i];
    float s = x[0] + x[1] + x[2] + x[3];
    float ss = x[0]*x[0] + x[1]*x[1] + x[2]*x[2] + x[3]*x[3];
    #pragma unroll
    for (int off = 32; off >= 1; off >>= 1) { s += __shfl_xor(s, off); ss += __shfl_xor(ss, off); }
    __shared__ float smem[8];
    int wave = t >> 6, lane = t & 63;
    if (lane == 0) { smem[wave] = s; smem[4 + wave] = ss; }
    __syncthreads();
    s  = smem[0] + smem[1] + smem[2] + smem[3];
    ss = smem[4] + smem[5] + smem[6] + smem[7];
    float mu  = s * (1.f / 1024.f);
    float var = ss * (1.f / 1024.f) - mu * mu;
    float rs  = rsqrtf(var + 1e-5f);
    float mv  = mask[row];
    floatx4 g4 = *(const floatx4*)&g[t * 4];
    floatx4 b4 = *(const floatx4*)&bb[t * 4];
    floatx4 y4;
    #pragma unroll
    for (int i = 0; i < 4; i++) y4[i] = ((x[i] - mu) * rs * g4[i] + b4[i]) * mv;
    *(floatx4*)&Out[base] = y4;
}

// ---------------------------------------------------------------------------
// Workspace map (high-water 44.75 MB, proven safe):
//   ws+0      q_b  4 MB  (-> ctx bf16 in place after combine)
//   ws+4 MB   k_b 12 MB  (dead after attn -> ao0 fp32 8 MB at ws+4)
//   ws+12 MB  (ao1 fp32 8 MB at ws+12, over k_b tail / vT head, both dead)
//   ws+16 MB  vT  12 MB  ([b][d][key] transposed V)
//   ws+28 MB  a_q 4 MB + a_kv 12 MB (cvt->proj; dead after)
//             -> pO_hi 16 MB (attn->combine; dead after)
//             -> wob 2 MB (cvt after combine -> gemm_out)
//   ws+44 MB  pml 0.75 MB
//   d_out 8 MB: wb bf16 6 MB (cvt->proj) -> pO_lo (attn->combine) -> output.
// ---------------------------------------------------------------------------
extern "C" void kernel_launch(void* const* d_in, const int* in_sizes, int n_in,
                              void* d_out, int out_size, void* d_ws, size_t ws_size,
                              hipStream_t stream) {
    (void)in_sizes; (void)n_in; (void)out_size; (void)ws_size;
    const float* h_q   = (const float*)d_in[0];
    const float* h_kv1 = (const float*)d_in[1];
    const float* h_kv2 = (const float*)d_in[2];
    const float* maskp = (const float*)d_in[3];
    const float* win   = (const float*)d_in[4];
    const float* binp  = (const float*)d_in[5];
    const float* wout  = (const float*)d_in[6];
    const float* bout  = (const float*)d_in[7];
    const float* ln_g  = (const float*)d_in[8];
    const float* ln_b  = (const float*)d_in[9];
    float* outp = (float*)d_out;

    char* ws = (char*)d_ws;
    const size_t MB = 1024 * 1024;
    u16*   q_b   = (u16*)(ws);
    u16*   k_b   = (u16*)(ws + 4 * MB);
    u16*   vT    = (u16*)(ws + 16 * MB);
    u16*   ctx_b = q_b;
    u16*   a_q   = (u16*)(ws + 28 * MB);
    u16*   a_kv  = (u16*)(ws + 32 * MB);
    u16*   wb    = (u16*)d_out;                // scratch until attn
    float* pO_lo = (float*)d_out;
    float* pO_hi = (float*)(ws + 28 * MB);
    u16*   wob   = (u16*)(ws + 28 * MB);       // after combine
    float* pml   = (float*)(ws + 44 * MB);
    float* ao0   = (float*)(ws + 4 * MB);
    float* ao1   = (float*)(ws + 12 * MB);

    cvt_all<<<2048, 256, 0, stream>>>(h_q, h_kv1, h_kv2, win, a_q, a_kv, wb);
    gemm_proj<<<896, 256, 0, stream>>>(a_q, a_kv, wb, binp, q_b, k_b, vT);
    attn_seg<<<1536, 256, 0, stream>>>(q_b, k_b, vT, pO_lo, pO_hi, pml);
    attn_combine<<<512, 256, 0, stream>>>(pO_lo, pO_hi, pml, ctx_b);
    cvt_bf16<<<512, 256, 0, stream>>>(wout, wob, 131072);
    gemm_out<<<256, 256, 0, stream>>>(ctx_b, wob, bout, ao0, ao1);
    ln_kernel<<<2048, 256, 0, stream>>>(ao0, ao1, h_q, ln_g, ln_b, maskp, outp);
}